// Round 14
// baseline (2456.104 us; speedup 1.0000x reference)
//
#include <hip/hip_runtime.h>

typedef __bf16 bf16;
typedef float f32x4 __attribute__((ext_vector_type(4)));
typedef __bf16 bf16x8 __attribute__((ext_vector_type(8)));
typedef __bf16 bf16x4 __attribute__((ext_vector_type(4)));

#define EPSF 1.1920928955078125e-07f

#define GLOAD_LDS16(gsrc, ldst) \
  __builtin_amdgcn_global_load_lds((const __attribute__((address_space(1))) void*)(gsrc), \
                                   (__attribute__((address_space(3))) void*)(ldst), 16, 0, 0)

__device__ __forceinline__ float wave_reduce_sum(float v) {
#pragma unroll
  for (int m = 1; m < 64; m <<= 1) v += __shfl_xor(v, m, 64);
  return v;
}

// ---------------- weight cast + transpose: src f32 [z][R][C] -> dst bf16 [z][C][R]
__global__ __launch_bounds__(256) void wcast_t(const float* __restrict__ src,
                                               bf16* __restrict__ dst, int R, int C) {
  __shared__ float t[32][33];
  int z = blockIdx.z;
  const float* s = src + (size_t)z * R * C;
  bf16* d = dst + (size_t)z * R * C;
  int c0 = blockIdx.x * 32, r0 = blockIdx.y * 32;
  int tx = threadIdx.x, ty = threadIdx.y;
#pragma unroll
  for (int k = 0; k < 4; ++k)
    t[ty + k * 8][tx] = s[(size_t)(r0 + ty + k * 8) * C + c0 + tx];
  __syncthreads();
#pragma unroll
  for (int k = 0; k < 4; ++k)
    d[(size_t)(c0 + ty + k * 8) * R + r0 + tx] = (bf16)t[tx][ty + k * 8];
}

// ---------------- RMSNorm: X f32 [rows][1536] * G -> O bf16
__global__ __launch_bounds__(256) void rmsnorm_k(const float* __restrict__ X,
                                                 const float* __restrict__ G,
                                                 bf16* __restrict__ O) {
  int row = blockIdx.x, tid = threadIdx.x, lane = tid & 63, w = tid >> 6;
  const float* x = X + (size_t)row * 1536;
  float v[6];
  float ss = 0.f;
#pragma unroll
  for (int k = 0; k < 6; ++k) { v[k] = x[tid + k * 256]; ss += v[k] * v[k]; }
  ss = wave_reduce_sum(ss);
  __shared__ float wsum[4];
  if (lane == 0) wsum[w] = ss;
  __syncthreads();
  ss = wsum[0] + wsum[1] + wsum[2] + wsum[3];
  float rs = rsqrtf(ss * (1.f / 1536.f) + EPSF);
  bf16* o = O + (size_t)row * 1536;
#pragma unroll
  for (int k = 0; k < 6; ++k) o[tid + k * 256] = (bf16)(v[k] * rs * G[tid + k * 256]);
}

// ---------------- GEMM 128x128, BK=64 (single-buffered, XCD-swizzled): ff1
// EPI: 2 = Cf += v; 3 = Cb = bf16(relu(v + bias)); 4 = Cf += v + bias; 5 = Cb = bf16(v)
template <int EPI>
__global__ __launch_bounds__(256, 3) void gemm_bt(const bf16* __restrict__ A,
                                                  const bf16* __restrict__ Bt,
                                                  float* __restrict__ Cf,
                                                  bf16* __restrict__ Cb,
                                                  const float* __restrict__ bias,
                                                  int M, int N, int K) {
  __shared__ __align__(16) char As[128 * 128];
  __shared__ __align__(16) char Bs[128 * 128];
  const int tid = threadIdx.x;
  const int lane = tid & 63, l15 = lane & 15, l4 = lane >> 4;
  const int w = tid >> 6;
  const int nwg = gridDim.x * gridDim.y;
  const int bid = blockIdx.y * gridDim.x + blockIdx.x;
  const int cpx = nwg >> 3;
  const int swz = (bid & 7) * cpx + (bid >> 3);
  const int rm = (swz / gridDim.x) * 128;
  const int cn = (swz % gridDim.x) * 128;
  const int wm = (w >> 1) * 64, wn = (w & 1) * 64;
  f32x4 acc[4][4] = {};

  for (int kk = 0; kk < K; kk += 64) {
#pragma unroll
    for (int r = 0; r < 4; ++r) {
      uint32_t o = (uint32_t)(r * 256 + tid) * 16;
      uint32_t row = o >> 7;
      uint32_t kb = ((o >> 4) & 7) ^ (row & 7);
      const bf16* src = A + (size_t)(rm + (int)row) * K + kk + kb * 8;
      GLOAD_LDS16(src, As + (o & 0xFFFFFC00u));
    }
#pragma unroll
    for (int r = 0; r < 4; ++r) {
      uint32_t o = (uint32_t)(r * 256 + tid) * 16;
      uint32_t row = o >> 7;
      uint32_t kb = ((o >> 4) & 7) ^ (row & 7);
      int nrow = cn + (int)row;
      if (nrow >= N) nrow = N - 1;
      const bf16* src = Bt + (size_t)nrow * K + kk + kb * 8;
      GLOAD_LDS16(src, Bs + (o & 0xFFFFFC00u));
    }
    __syncthreads();
#pragma unroll
    for (int s = 0; s < 2; ++s) {
      bf16x8 a[4], b[4];
#pragma unroll
      for (int m = 0; m < 4; ++m) {
        uint32_t row = wm + m * 16 + l15;
        uint32_t kb = (uint32_t)(s * 4 + l4);
        a[m] = *(const bf16x8*)(As + row * 128 + (kb ^ (row & 7)) * 16);
      }
#pragma unroll
      for (int n = 0; n < 4; ++n) {
        uint32_t row = wn + n * 16 + l15;
        uint32_t kb = (uint32_t)(s * 4 + l4);
        b[n] = *(const bf16x8*)(Bs + row * 128 + (kb ^ (row & 7)) * 16);
      }
      __builtin_amdgcn_s_setprio(1);
#pragma unroll
      for (int m = 0; m < 4; ++m)
#pragma unroll
        for (int n = 0; n < 4; ++n)
          acc[m][n] = __builtin_amdgcn_mfma_f32_16x16x32_bf16(a[m], b[n], acc[m][n], 0, 0, 0);
      __builtin_amdgcn_s_setprio(0);
    }
    __syncthreads();
  }

#pragma unroll
  for (int m = 0; m < 4; ++m)
#pragma unroll
    for (int n = 0; n < 4; ++n)
#pragma unroll
      for (int r = 0; r < 4; ++r) {
        int row = rm + wm + m * 16 + l4 * 4 + r;
        int col = cn + wn + n * 16 + l15;
        if (col < N) {
          float v = acc[m][n][r];
          size_t idx = (size_t)row * N + col;
          if constexpr (EPI == 2) {
            Cf[idx] += v;
          } else if constexpr (EPI == 3) {
            float tv = v + bias[col];
            Cb[idx] = (bf16)(tv > 0.f ? tv : 0.f);
          } else if constexpr (EPI == 4) {
            Cf[idx] += v + bias[col];
          } else if constexpr (EPI == 5) {
            Cb[idx] = (bf16)v;
          }
        }
      }
}

// ---------------- GEMM 64x128, BK=64, 2-phase double-buffered (LDS 48KB, 3 blocks/CU)
// qkv / out / ff2. STAGE(t+1) overlaps COMPUTE(t); one barrier per tile.
template <int EPI>
__global__ __launch_bounds__(256, 3) void gemm_bt64(const bf16* __restrict__ A,
                                                    const bf16* __restrict__ Bt,
                                                    float* __restrict__ Cf,
                                                    bf16* __restrict__ Cb,
                                                    const float* __restrict__ bias,
                                                    int M, int N, int K) {
  __shared__ __align__(16) char As[2][64 * 128];
  __shared__ __align__(16) char Bs[2][128 * 128];
  const int tid = threadIdx.x;
  const int lane = tid & 63, l15 = lane & 15, l4 = lane >> 4;
  const int w = tid >> 6;
  const int nwg = gridDim.x * gridDim.y;
  const int bid = blockIdx.y * gridDim.x + blockIdx.x;
  const int cpx = nwg >> 3;
  const int swz = (bid & 7) * cpx + (bid >> 3);
  const int rm = (swz / gridDim.x) * 64;
  const int cn = (swz % gridDim.x) * 128;
  const int wm = (w >> 1) * 32, wn = (w & 1) * 64;
  f32x4 acc[2][4] = {};

  auto STAGE = [&](int buf, int kk) {
#pragma unroll
    for (int r = 0; r < 2; ++r) {
      uint32_t o = (uint32_t)(r * 256 + tid) * 16;
      uint32_t row = o >> 7;
      uint32_t kb = ((o >> 4) & 7) ^ (row & 7);
      const bf16* src = A + (size_t)(rm + (int)row) * K + kk + kb * 8;
      GLOAD_LDS16(src, &As[buf][0] + (o & 0xFFFFFC00u));
    }
#pragma unroll
    for (int r = 0; r < 4; ++r) {
      uint32_t o = (uint32_t)(r * 256 + tid) * 16;
      uint32_t row = o >> 7;
      uint32_t kb = ((o >> 4) & 7) ^ (row & 7);
      int nrow = cn + (int)row;
      if (nrow >= N) nrow = N - 1;
      const bf16* src = Bt + (size_t)nrow * K + kk + kb * 8;
      GLOAD_LDS16(src, &Bs[buf][0] + (o & 0xFFFFFC00u));
    }
  };

  auto COMPUTE = [&](int buf) {
#pragma unroll
    for (int s = 0; s < 2; ++s) {
      bf16x8 a[2], b[4];
#pragma unroll
      for (int m = 0; m < 2; ++m) {
        uint32_t row = wm + m * 16 + l15;
        uint32_t kb = (uint32_t)(s * 4 + l4);
        a[m] = *(const bf16x8*)(&As[buf][0] + row * 128 + (kb ^ (row & 7)) * 16);
      }
#pragma unroll
      for (int n = 0; n < 4; ++n) {
        uint32_t row = wn + n * 16 + l15;
        uint32_t kb = (uint32_t)(s * 4 + l4);
        b[n] = *(const bf16x8*)(&Bs[buf][0] + row * 128 + (kb ^ (row & 7)) * 16);
      }
      __builtin_amdgcn_s_setprio(1);
#pragma unroll
      for (int m = 0; m < 2; ++m)
#pragma unroll
        for (int n = 0; n < 4; ++n)
          acc[m][n] = __builtin_amdgcn_mfma_f32_16x16x32_bf16(a[m], b[n], acc[m][n], 0, 0, 0);
      __builtin_amdgcn_s_setprio(0);
    }
  };

  STAGE(0, 0);
  __syncthreads();
  int cur = 0;
  for (int kk = 64; kk < K; kk += 64) {
    STAGE(cur ^ 1, kk);   // next tile's loads fly during this tile's compute
    COMPUTE(cur);
    __syncthreads();      // joint barrier: readers done + next buffer's loads drained
    cur ^= 1;
  }
  COMPUTE(cur);

#pragma unroll
  for (int m = 0; m < 2; ++m)
#pragma unroll
    for (int n = 0; n < 4; ++n)
#pragma unroll
      for (int r = 0; r < 4; ++r) {
        int row = rm + wm + m * 16 + l4 * 4 + r;
        int col = cn + wn + n * 16 + l15;
        if (col < N) {
          float v = acc[m][n][r];
          size_t idx = (size_t)row * N + col;
          if constexpr (EPI == 2) {
            Cf[idx] += v;
          } else if constexpr (EPI == 3) {
            float tv = v + bias[col];
            Cb[idx] = (bf16)(tv > 0.f ? tv : 0.f);
          } else if constexpr (EPI == 4) {
            Cf[idx] += v + bias[col];
          } else if constexpr (EPI == 5) {
            Cb[idx] = (bf16)v;
          }
        }
      }
}

// ---------------- QKV postprocess (4 tokens/block): per (token, segment) RMSNorm (+scale+rope)
__global__ __launch_bounds__(256) void qkv_post(const bf16* __restrict__ qkv,
                                                const float* __restrict__ qg,
                                                const float* __restrict__ kg,
                                                const float* __restrict__ vg,
                                                bf16* __restrict__ Qo, bf16* __restrict__ Ko,
                                                bf16* __restrict__ Vo) {
  int lane = threadIdx.x & 63, wv = threadIdx.x >> 6;
  int t = blockIdx.x * 4 + wv, seg = blockIdx.y;
  int b = t >> 11, n = t & 2047;
  const bf16* base;
  const float* gamma;
  int len;
  if (seg < 8) { base = qkv + (size_t)t * 1344 + seg * 128; gamma = qg; len = 128; }
  else if (seg == 8) { base = qkv + (size_t)t * 1344 + 1024; gamma = kg; len = 128; }
  else { base = qkv + (size_t)t * 1344 + 1152; gamma = vg; len = 192; }
  float v0 = (float)base[lane], v1 = (float)base[lane + 64];
  float v2 = (len == 192) ? (float)base[lane + 128] : 0.f;
  float ss = wave_reduce_sum(v0 * v0 + v1 * v1 + v2 * v2);
  float rs = rsqrtf(ss / (float)len + EPSF);
  float n0 = v0 * rs * gamma[lane];
  float n1 = v1 * rs * gamma[lane + 64];
  if (seg < 8) {
    n0 *= 0.125f; n1 *= 0.125f;
    if (lane == 0) {
      float th = 0.1f * (float)n;
      float c = cosf(th), s_ = sinf(th);
      float r0 = n0 * c - n1 * s_, r1 = n1 * c + n0 * s_;
      n0 = r0; n1 = r1;
    }
    bf16* q = Qo + ((size_t)((b * 8 + seg) * 2048 + n)) * 128;
    q[lane] = (bf16)n0; q[lane + 64] = (bf16)n1;
  } else if (seg == 8) {
    if (lane == 0) {
      float th = 0.1f * (float)n;
      float c = cosf(th), s_ = sinf(th);
      float r0 = n0 * c - n1 * s_, r1 = n1 * c + n0 * s_;
      n0 = r0; n1 = r1;
    }
    bf16* k = Ko + ((size_t)(b * 2048 + n)) * 128;
    k[lane] = (bf16)n0; k[lane + 64] = (bf16)n1;
  } else {
    float n2 = v2 * rs * vg[lane + 128];
    bf16* vp = Vo + ((size_t)(b * 2048 + n)) * 192;
    vp[lane] = (bf16)n0; vp[lane + 64] = (bf16)n1; vp[lane + 128] = (bf16)n2;
  }
}

// ---------------- V transpose: V bf16 [2][2048][192] -> Vt [2][192][2048]
__global__ __launch_bounds__(256) void vtrans(const bf16* __restrict__ V, bf16* __restrict__ Vt) {
  __shared__ bf16 t[32][33];
  int b = blockIdx.z;
  int j0 = blockIdx.x * 32, d0 = blockIdx.y * 32;
  int tx = threadIdx.x, ty = threadIdx.y;
#pragma unroll
  for (int k = 0; k < 4; ++k)
    t[ty + k * 8][tx] = V[((size_t)b * 2048 + j0 + ty + k * 8) * 192 + d0 + tx];
  __syncthreads();
#pragma unroll
  for (int k = 0; k < 4; ++k)
    Vt[((size_t)b * 192 + d0 + ty + k * 8) * 2048 + j0 + tx] = t[tx][ty + k * 8];
}

// ---------------- pairwise bias, all 8 layers batched:
// pn = p * rsqrt(mean(p^2)+eps) once; per layer: gelu(pn*g_d) @ Wb_d
// Bout layout [d][b][h][128][128] f32
__global__ void bias_pw8(const float* __restrict__ P, const float* __restrict__ G8,
                         const float* __restrict__ Wb8, float* __restrict__ Bout) {
  int j = blockIdx.x, i = blockIdx.y, b = blockIdx.z;
  int lane = threadIdx.x;
  const float* p = P + (((size_t)b * 128 + i) * 128 + j) * 128;
  float a0 = p[lane], a1 = p[lane + 64];
  float ss = wave_reduce_sum(a0 * a0 + a1 * a1);
  float rs = rsqrtf(ss * (1.f / 128.f) + EPSF);
  float pn0 = a0 * rs, pn1 = a1 * rs;
  __shared__ float gs[128];
  for (int d = 0; d < 8; ++d) {
    float x0 = pn0 * G8[d * 128 + lane], x1 = pn1 * G8[d * 128 + lane + 64];
    float g0 = 0.5f * x0 * (1.f + erff(x0 * 0.70710678118654752f));
    float g1 = 0.5f * x1 * (1.f + erff(x1 * 0.70710678118654752f));
    __syncthreads();
    gs[lane] = g0; gs[lane + 64] = g1;
    __syncthreads();
    int h = lane & 7;
    float acc = 0.f;
#pragma unroll
    for (int k = 0; k < 16; ++k) {
      int c = (lane >> 3) + k * 8;
      acc += gs[c] * Wb8[((size_t)d * 128 + c) * 8 + h];
    }
    acc += __shfl_xor(acc, 8, 64);
    acc += __shfl_xor(acc, 16, 64);
    acc += __shfl_xor(acc, 32, 64);
    if (lane < 8)
      Bout[((((size_t)d * 2 + b) * 8 + lane) * 128 + i) * 128 + j] = acc;
  }
}

// ---------------- attention (BI=64, full KV sweep, direct normalized output)
__global__ __launch_bounds__(256, 3) void attn_k(const bf16* __restrict__ Q,
                                                 const bf16* __restrict__ Kg,
                                                 const bf16* __restrict__ Vt,
                                                 const float* __restrict__ Bias,
                                                 bf16* __restrict__ Out) {
  __shared__ __align__(16) char Ks[64 * 256];  // [64 j][128 k] swz16
  __shared__ __align__(16) char Vs[192 * 128]; // [192 dv][64 j] swz8
  __shared__ __align__(16) char Ps[64 * 128];  // [64 i][64 j] bf16, swz8 by (row&7)
  __shared__ float BiasS[4 * 128];             // pre-scaled by 0.57707801
  int tid = threadIdx.x, lane = tid & 63, w = tid >> 6;
  int it = blockIdx.x, g = blockIdx.y, b = blockIdx.z;
  int i0 = it * 64;
  int l15 = lane & 15, l4 = lane >> 4;

  bf16x8 qf[4];
#pragma unroll
  for (int s = 0; s < 4; ++s)
    qf[s] = *(const bf16x8*)(Q + ((size_t)((b * 8 + g) * 2048 + i0 + w * 16 + l15)) * 128 + s * 32 + l4 * 8);

  if (tid < 128) {
    int r = tid >> 5, c = (tid & 31) * 4;
    float4 bv = *(const float4*)(Bias + ((size_t)((b * 8 + g) * 128) + (i0 >> 4) + r) * 128 + c);
    bv.x *= 0.57707801635558535f; bv.y *= 0.57707801635558535f;
    bv.z *= 0.57707801635558535f; bv.w *= 0.57707801635558535f;
    *(float4*)&BiasS[r * 128 + c] = bv;
  }

  f32x4 accO[12] = {};
  float lacc = 0.f;

  for (int jt = 0; jt < 32; ++jt) {
    int j0 = jt * 64;
#pragma unroll
    for (int r = 0; r < 4; ++r) {
      uint32_t o = (uint32_t)(r * 256 + tid) * 16;
      uint32_t row = o >> 8;
      uint32_t kb = ((o >> 4) & 15) ^ (row & 15);
      const bf16* src = Kg + ((size_t)b * 2048 + j0 + (int)row) * 128 + kb * 8;
      GLOAD_LDS16(src, Ks + (o & 0xFFFFFC00u));
    }
#pragma unroll
    for (int r = 0; r < 6; ++r) {
      uint32_t o = (uint32_t)(r * 256 + tid) * 16;
      uint32_t dv = o >> 7;
      uint32_t kb = ((o >> 4) & 7) ^ (dv & 7);
      const bf16* src = Vt + ((size_t)b * 192 + dv) * 2048 + j0 + kb * 8;
      GLOAD_LDS16(src, Vs + (o & 0xFFFFFC00u));
    }
    __syncthreads();

    // QK^T swapped: accS[n] = mfma(kf[n], qf[s])  (row=j, col=i=l15)
    f32x4 accS[4] = {};
#pragma unroll
    for (int s = 0; s < 4; ++s) {
      bf16x8 kf[4];
#pragma unroll
      for (int n = 0; n < 4; ++n) {
        uint32_t row = n * 16 + l15;
        uint32_t kb = (uint32_t)(s * 4 + l4);
        kf[n] = *(const bf16x8*)(Ks + row * 256 + (kb ^ (row & 15)) * 16);
      }
      __builtin_amdgcn_s_setprio(1);
#pragma unroll
      for (int n = 0; n < 4; ++n)
        accS[n] = __builtin_amdgcn_mfma_f32_16x16x32_bf16(kf[n], qf[s], accS[n], 0, 0, 0);
      __builtin_amdgcn_s_setprio(0);
    }

    // softclamp + exp -> packed b64 P-writes + per-lane sums
#pragma unroll
    for (int n = 0; n < 4; ++n) {
      float biaS = BiasS[w * 128 + jt * 4 + n];
      bf16x4 pk;
#pragma unroll
      for (int r = 0; r < 4; ++r) {
        float t1 = __builtin_fmaf(0.57707801635558535f, accS[n][r], biaS);
        float e1 = exp2f(t1);
        float rr = __builtin_amdgcn_rcpf(e1 + 1.0f);
        float pv = exp2f(-14.426950408889634f * rr);
        lacc += pv;
        pk[r] = (bf16)pv;
      }
      uint32_t prow = (uint32_t)(w * 16 + l15);
      uint32_t byteo = prow * 128 + (uint32_t)(n * 16 + l4 * 4) * 2;
      byteo ^= (prow & 7) << 4;
      *(bf16x4*)(Ps + byteo) = pk;
    }

    // PV swapped: accO[n] = mfma(vf, pa)  (row=dv, col=i)
#pragma unroll
    for (int s = 0; s < 2; ++s) {
      uint32_t prow = (uint32_t)(w * 16 + l15);
      uint32_t byteo = prow * 128 + (uint32_t)(s * 64 + l4 * 16);
      byteo ^= (prow & 7) << 4;
      bf16x8 pa = *(const bf16x8*)(Ps + byteo);
#pragma unroll
      for (int n = 0; n < 12; ++n) {
        uint32_t dvr = n * 16 + l15;
        uint32_t kb = (uint32_t)(s * 4 + l4);
        bf16x8 vf = *(const bf16x8*)(Vs + dvr * 128 + (kb ^ (dvr & 7)) * 16);
        __builtin_amdgcn_s_setprio(1);
        accO[n] = __builtin_amdgcn_mfma_f32_16x16x32_bf16(vf, pa, accO[n], 0, 0, 0);
        __builtin_amdgcn_s_setprio(0);
      }
    }
    __syncthreads();
  }

  lacc += __shfl_xor(lacc, 16, 64);
  lacc += __shfl_xor(lacc, 32, 64);
  float rl = __builtin_amdgcn_rcpf(lacc);

  {
    int i = i0 + w * 16 + l15;
#pragma unroll
    for (int n = 0; n < 12; ++n) {
      bf16x4 ok;
#pragma unroll
      for (int r = 0; r < 4; ++r) ok[r] = (bf16)(accO[n][r] * rl);
      int dv = n * 16 + l4 * 4;
      *(bf16x4*)(Out + ((size_t)(b * 2048 + i)) * 1536 + g * 192 + dv) = ok;
    }
  }
}

// =============================================================================
extern "C" void kernel_launch(void* const* d_in, const int* in_sizes, int n_in,
                              void* d_out, int out_size, void* d_ws, size_t ws_size,
                              hipStream_t stream) {
  (void)in_sizes; (void)n_in; (void)out_size;
  const float* x_in = (const float*)d_in[0];
  const float* pairwise = (const float*)d_in[1];
  const float* w_qkv = (const float*)d_in[2];
  const float* q_gamma = (const float*)d_in[3];
  const float* k_gamma = (const float*)d_in[4];
  const float* v_gamma = (const float*)d_in[5];
  const float* bias_gamma = (const float*)d_in[6];
  const float* w_bias = (const float*)d_in[7];
  const float* w_out = (const float*)d_in[8];
  const float* attn_pre = (const float*)d_in[9];
  const float* ff_pre = (const float*)d_in[10];
  const float* w_ff1 = (const float*)d_in[11];
  const float* b_ff1 = (const float*)d_in[12];
  const float* w_ff2 = (const float*)d_in[13];
  const float* b_ff2 = (const float*)d_in[14];

  char* p = (char*)d_ws;
  auto alloc = [&](size_t bytes) {
    char* r = p;
    p += (bytes + 255) & ~(size_t)255;
    return r;
  };
  bf16* wT_qkv = (bf16*)alloc(8ull * 1344 * 1536 * 2);
  bf16* wT_out = (bf16*)alloc(8ull * 1536 * 1536 * 2);
  bf16* wT_ff1 = (bf16*)alloc(8ull * 3072 * 1536 * 2);
  bf16* wT_ff2 = (bf16*)alloc(8ull * 1536 * 3072 * 2);
  float* x_ws = (float*)alloc(4096ull * 1536 * 4);
  bf16* xn = (bf16*)alloc(4096ull * 1536 * 2);
  bf16* qkvb = (bf16*)alloc(4096ull * 1344 * 2);
  bf16* qb = (bf16*)alloc(2ull * 8 * 2048 * 128 * 2);
  bf16* kb = (bf16*)alloc(2ull * 2048 * 128 * 2);
  bf16* vb = (bf16*)alloc(2ull * 2048 * 192 * 2);
  bf16* vtb = (bf16*)alloc(2ull * 192 * 2048 * 2);
  float* biasb8 = (float*)alloc(8ull * 2 * 8 * 128 * 128 * 4);
  bf16* attn_o = (bf16*)alloc(4096ull * 1536 * 2);
  bf16* hb = (bf16*)alloc(4096ull * 3072 * 2);
  if ((size_t)(p - (char*)d_ws) > ws_size) return;  // workspace too small

  // weight casts (transposed to [N][K] bf16)
  wcast_t<<<dim3(42, 48, 8), dim3(32, 8), 0, stream>>>(w_qkv, wT_qkv, 1536, 1344);
  wcast_t<<<dim3(48, 48, 8), dim3(32, 8), 0, stream>>>(w_out, wT_out, 1536, 1536);
  wcast_t<<<dim3(96, 48, 8), dim3(32, 8), 0, stream>>>(w_ff1, wT_ff1, 1536, 3072);
  wcast_t<<<dim3(48, 96, 8), dim3(32, 8), 0, stream>>>(w_ff2, wT_ff2, 3072, 1536);

  // all-layer pairwise bias (amortizes pairwise load + rmsnorm across 8 layers)
  bias_pw8<<<dim3(128, 128, 2), 64, 0, stream>>>(pairwise, bias_gamma, w_bias, biasb8);

  hipMemcpyAsync(x_ws, x_in, 4096ull * 1536 * 4, hipMemcpyDeviceToDevice, stream);

  for (int d = 0; d < 8; ++d) {
    const bf16* wq = wT_qkv + (size_t)d * 1344 * 1536;
    const bf16* wo = wT_out + (size_t)d * 1536 * 1536;
    const bf16* w1 = wT_ff1 + (size_t)d * 3072 * 1536;
    const bf16* w2 = wT_ff2 + (size_t)d * 1536 * 3072;

    rmsnorm_k<<<4096, 256, 0, stream>>>(x_ws, attn_pre + d * 1536, xn);
    gemm_bt64<5><<<dim3(11, 64), 256, 0, stream>>>(xn, wq, nullptr, qkvb, nullptr, 4096, 1344, 1536);
    qkv_post<<<dim3(1024, 10), 256, 0, stream>>>(qkvb, q_gamma + d * 128, k_gamma + d * 128,
                                                 v_gamma + d * 192, qb, kb, vb);
    vtrans<<<dim3(64, 6, 2), dim3(32, 8), 0, stream>>>(vb, vtb);
    attn_k<<<dim3(32, 8, 2), 256, 0, stream>>>(qb, kb, vtb,
                                               biasb8 + (size_t)d * 2 * 8 * 128 * 128, attn_o);
    gemm_bt64<2><<<dim3(12, 64), 256, 0, stream>>>(attn_o, wo, x_ws, nullptr, nullptr, 4096, 1536, 1536);
    rmsnorm_k<<<4096, 256, 0, stream>>>(x_ws, ff_pre + d * 1536, xn);
    gemm_bt<3><<<dim3(24, 32), 256, 0, stream>>>(xn, w1, nullptr, hb, b_ff1 + d * 3072, 4096, 3072, 1536);
    gemm_bt64<4><<<dim3(12, 64), 256, 0, stream>>>(hb, w2, x_ws, nullptr, b_ff2 + d * 1536, 4096, 1536, 3072);
  }

  hipMemcpyAsync(d_out, x_ws, 4096ull * 1536 * 4, hipMemcpyDeviceToDevice, stream);
}

// Round 15
// 2381.792 us; speedup vs baseline: 1.0312x; 1.0312x over previous
//
#include <hip/hip_runtime.h>

typedef __bf16 bf16;
typedef float f32x4 __attribute__((ext_vector_type(4)));
typedef __bf16 bf16x8 __attribute__((ext_vector_type(8)));
typedef __bf16 bf16x4 __attribute__((ext_vector_type(4)));

#define EPSF 1.1920928955078125e-07f

#define GLOAD_LDS16(gsrc, ldst) \
  __builtin_amdgcn_global_load_lds((const __attribute__((address_space(1))) void*)(gsrc), \
                                   (__attribute__((address_space(3))) void*)(ldst), 16, 0, 0)

__device__ __forceinline__ float wave_reduce_sum(float v) {
#pragma unroll
  for (int m = 1; m < 64; m <<= 1) v += __shfl_xor(v, m, 64);
  return v;
}

// ---------------- weight cast + transpose: src f32 [z][R][C] -> dst bf16 [z][C][R]
__global__ __launch_bounds__(256) void wcast_t(const float* __restrict__ src,
                                               bf16* __restrict__ dst, int R, int C) {
  __shared__ float t[32][33];
  int z = blockIdx.z;
  const float* s = src + (size_t)z * R * C;
  bf16* d = dst + (size_t)z * R * C;
  int c0 = blockIdx.x * 32, r0 = blockIdx.y * 32;
  int tx = threadIdx.x, ty = threadIdx.y;
#pragma unroll
  for (int k = 0; k < 4; ++k)
    t[ty + k * 8][tx] = s[(size_t)(r0 + ty + k * 8) * C + c0 + tx];
  __syncthreads();
#pragma unroll
  for (int k = 0; k < 4; ++k)
    d[(size_t)(c0 + ty + k * 8) * R + r0 + tx] = (bf16)t[tx][ty + k * 8];
}

// ---------------- RMSNorm: X f32 [rows][1536] * G -> O bf16
__global__ __launch_bounds__(256) void rmsnorm_k(const float* __restrict__ X,
                                                 const float* __restrict__ G,
                                                 bf16* __restrict__ O) {
  int row = blockIdx.x, tid = threadIdx.x, lane = tid & 63, w = tid >> 6;
  const float* x = X + (size_t)row * 1536;
  float v[6];
  float ss = 0.f;
#pragma unroll
  for (int k = 0; k < 6; ++k) { v[k] = x[tid + k * 256]; ss += v[k] * v[k]; }
  ss = wave_reduce_sum(ss);
  __shared__ float wsum[4];
  if (lane == 0) wsum[w] = ss;
  __syncthreads();
  ss = wsum[0] + wsum[1] + wsum[2] + wsum[3];
  float rs = rsqrtf(ss * (1.f / 1536.f) + EPSF);
  bf16* o = O + (size_t)row * 1536;
#pragma unroll
  for (int k = 0; k < 6; ++k) o[tid + k * 256] = (bf16)(v[k] * rs * G[tid + k * 256]);
}

// ---------------- GEMM 128x128, BK=64 (single-buffered, XCD-swizzled): ff1
// EPI: 2 = Cf += v; 3 = Cb = bf16(relu(v + bias)); 4 = Cf += v + bias; 5 = Cb = bf16(v)
template <int EPI>
__global__ __launch_bounds__(256, 3) void gemm_bt(const bf16* __restrict__ A,
                                                  const bf16* __restrict__ Bt,
                                                  float* __restrict__ Cf,
                                                  bf16* __restrict__ Cb,
                                                  const float* __restrict__ bias,
                                                  int M, int N, int K) {
  __shared__ __align__(16) char As[128 * 128];
  __shared__ __align__(16) char Bs[128 * 128];
  const int tid = threadIdx.x;
  const int lane = tid & 63, l15 = lane & 15, l4 = lane >> 4;
  const int w = tid >> 6;
  const int nwg = gridDim.x * gridDim.y;
  const int bid = blockIdx.y * gridDim.x + blockIdx.x;
  const int cpx = nwg >> 3;
  const int swz = (bid & 7) * cpx + (bid >> 3);
  const int rm = (swz / gridDim.x) * 128;
  const int cn = (swz % gridDim.x) * 128;
  const int wm = (w >> 1) * 64, wn = (w & 1) * 64;
  f32x4 acc[4][4] = {};

  for (int kk = 0; kk < K; kk += 64) {
#pragma unroll
    for (int r = 0; r < 4; ++r) {
      uint32_t o = (uint32_t)(r * 256 + tid) * 16;
      uint32_t row = o >> 7;
      uint32_t kb = ((o >> 4) & 7) ^ (row & 7);
      const bf16* src = A + (size_t)(rm + (int)row) * K + kk + kb * 8;
      GLOAD_LDS16(src, As + (o & 0xFFFFFC00u));
    }
#pragma unroll
    for (int r = 0; r < 4; ++r) {
      uint32_t o = (uint32_t)(r * 256 + tid) * 16;
      uint32_t row = o >> 7;
      uint32_t kb = ((o >> 4) & 7) ^ (row & 7);
      int nrow = cn + (int)row;
      if (nrow >= N) nrow = N - 1;
      const bf16* src = Bt + (size_t)nrow * K + kk + kb * 8;
      GLOAD_LDS16(src, Bs + (o & 0xFFFFFC00u));
    }
    __syncthreads();
#pragma unroll
    for (int s = 0; s < 2; ++s) {
      bf16x8 a[4], b[4];
#pragma unroll
      for (int m = 0; m < 4; ++m) {
        uint32_t row = wm + m * 16 + l15;
        uint32_t kb = (uint32_t)(s * 4 + l4);
        a[m] = *(const bf16x8*)(As + row * 128 + (kb ^ (row & 7)) * 16);
      }
#pragma unroll
      for (int n = 0; n < 4; ++n) {
        uint32_t row = wn + n * 16 + l15;
        uint32_t kb = (uint32_t)(s * 4 + l4);
        b[n] = *(const bf16x8*)(Bs + row * 128 + (kb ^ (row & 7)) * 16);
      }
      __builtin_amdgcn_s_setprio(1);
#pragma unroll
      for (int m = 0; m < 4; ++m)
#pragma unroll
        for (int n = 0; n < 4; ++n)
          acc[m][n] = __builtin_amdgcn_mfma_f32_16x16x32_bf16(a[m], b[n], acc[m][n], 0, 0, 0);
      __builtin_amdgcn_s_setprio(0);
    }
    __syncthreads();
  }

#pragma unroll
  for (int m = 0; m < 4; ++m)
#pragma unroll
    for (int n = 0; n < 4; ++n)
#pragma unroll
      for (int r = 0; r < 4; ++r) {
        int row = rm + wm + m * 16 + l4 * 4 + r;
        int col = cn + wn + n * 16 + l15;
        if (col < N) {
          float v = acc[m][n][r];
          size_t idx = (size_t)row * N + col;
          if constexpr (EPI == 2) {
            Cf[idx] += v;
          } else if constexpr (EPI == 3) {
            float tv = v + bias[col];
            Cb[idx] = (bf16)(tv > 0.f ? tv : 0.f);
          } else if constexpr (EPI == 4) {
            Cf[idx] += v + bias[col];
          } else if constexpr (EPI == 5) {
            Cb[idx] = (bf16)v;
          }
        }
      }
}

// ---------------- GEMM 64x128 tile, BK=128 (LDS 48KB, 3 blocks/CU): qkv / out / ff2
// Rows are 256B (128 bf16); swz16 staging pattern (identical to attn Ks layout).
template <int EPI>
__global__ __launch_bounds__(256, 3) void gemm_bt64(const bf16* __restrict__ A,
                                                    const bf16* __restrict__ Bt,
                                                    float* __restrict__ Cf,
                                                    bf16* __restrict__ Cb,
                                                    const float* __restrict__ bias,
                                                    int M, int N, int K) {
  __shared__ __align__(16) char As[64 * 256];   // [64 m][128 k] swz16
  __shared__ __align__(16) char Bs[128 * 256];  // [128 n][128 k] swz16
  const int tid = threadIdx.x;
  const int lane = tid & 63, l15 = lane & 15, l4 = lane >> 4;
  const int w = tid >> 6;
  const int nwg = gridDim.x * gridDim.y;
  const int bid = blockIdx.y * gridDim.x + blockIdx.x;
  const int cpx = nwg >> 3;
  const int swz = (bid & 7) * cpx + (bid >> 3);
  const int rm = (swz / gridDim.x) * 64;
  const int cn = (swz % gridDim.x) * 128;
  const int wm = (w >> 1) * 32, wn = (w & 1) * 64;
  f32x4 acc[2][4] = {};

  for (int kk = 0; kk < K; kk += 128) {
#pragma unroll
    for (int r = 0; r < 4; ++r) {
      uint32_t o = (uint32_t)(r * 256 + tid) * 16;
      uint32_t row = o >> 8;
      uint32_t kb = ((o >> 4) & 15) ^ (row & 15);
      const bf16* src = A + (size_t)(rm + (int)row) * K + kk + kb * 8;
      GLOAD_LDS16(src, As + (o & 0xFFFFF800u) + ((o & 0x7F0u)));
    }
#pragma unroll
    for (int r = 0; r < 8; ++r) {
      uint32_t o = (uint32_t)(r * 256 + tid) * 16;
      uint32_t row = o >> 8;
      uint32_t kb = ((o >> 4) & 15) ^ (row & 15);
      int nrow = cn + (int)row;
      if (nrow >= N) nrow = N - 1;
      const bf16* src = Bt + (size_t)nrow * K + kk + kb * 8;
      GLOAD_LDS16(src, Bs + (o & 0xFFFFF800u) + ((o & 0x7F0u)));
    }
    __syncthreads();
#pragma unroll
    for (int s = 0; s < 4; ++s) {
      bf16x8 a[2], b[4];
#pragma unroll
      for (int m = 0; m < 2; ++m) {
        uint32_t row = wm + m * 16 + l15;
        uint32_t kb = (uint32_t)(s * 4 + l4);
        a[m] = *(const bf16x8*)(As + row * 256 + ((kb ^ (row & 15)) * 16));
      }
#pragma unroll
      for (int n = 0; n < 4; ++n) {
        uint32_t row = wn + n * 16 + l15;
        uint32_t kb = (uint32_t)(s * 4 + l4);
        b[n] = *(const bf16x8*)(Bs + row * 256 + ((kb ^ (row & 15)) * 16));
      }
      __builtin_amdgcn_s_setprio(1);
#pragma unroll
      for (int m = 0; m < 2; ++m)
#pragma unroll
        for (int n = 0; n < 4; ++n)
          acc[m][n] = __builtin_amdgcn_mfma_f32_16x16x32_bf16(a[m], b[n], acc[m][n], 0, 0, 0);
      __builtin_amdgcn_s_setprio(0);
    }
    __syncthreads();
  }

#pragma unroll
  for (int m = 0; m < 2; ++m)
#pragma unroll
    for (int n = 0; n < 4; ++n)
#pragma unroll
      for (int r = 0; r < 4; ++r) {
        int row = rm + wm + m * 16 + l4 * 4 + r;
        int col = cn + wn + n * 16 + l15;
        if (col < N) {
          float v = acc[m][n][r];
          size_t idx = (size_t)row * N + col;
          if constexpr (EPI == 2) {
            Cf[idx] += v;
          } else if constexpr (EPI == 3) {
            float tv = v + bias[col];
            Cb[idx] = (bf16)(tv > 0.f ? tv : 0.f);
          } else if constexpr (EPI == 4) {
            Cf[idx] += v + bias[col];
          } else if constexpr (EPI == 5) {
            Cb[idx] = (bf16)v;
          }
        }
      }
}

// ---------------- QKV postprocess (4 tokens/block): per (token, segment) RMSNorm (+scale+rope)
__global__ __launch_bounds__(256) void qkv_post(const bf16* __restrict__ qkv,
                                                const float* __restrict__ qg,
                                                const float* __restrict__ kg,
                                                const float* __restrict__ vg,
                                                bf16* __restrict__ Qo, bf16* __restrict__ Ko,
                                                bf16* __restrict__ Vo) {
  int lane = threadIdx.x & 63, wv = threadIdx.x >> 6;
  int t = blockIdx.x * 4 + wv, seg = blockIdx.y;
  int b = t >> 11, n = t & 2047;
  const bf16* base;
  const float* gamma;
  int len;
  if (seg < 8) { base = qkv + (size_t)t * 1344 + seg * 128; gamma = qg; len = 128; }
  else if (seg == 8) { base = qkv + (size_t)t * 1344 + 1024; gamma = kg; len = 128; }
  else { base = qkv + (size_t)t * 1344 + 1152; gamma = vg; len = 192; }
  float v0 = (float)base[lane], v1 = (float)base[lane + 64];
  float v2 = (len == 192) ? (float)base[lane + 128] : 0.f;
  float ss = wave_reduce_sum(v0 * v0 + v1 * v1 + v2 * v2);
  float rs = rsqrtf(ss / (float)len + EPSF);
  float n0 = v0 * rs * gamma[lane];
  float n1 = v1 * rs * gamma[lane + 64];
  if (seg < 8) {
    n0 *= 0.125f; n1 *= 0.125f;
    if (lane == 0) {
      float th = 0.1f * (float)n;
      float c = cosf(th), s_ = sinf(th);
      float r0 = n0 * c - n1 * s_, r1 = n1 * c + n0 * s_;
      n0 = r0; n1 = r1;
    }
    bf16* q = Qo + ((size_t)((b * 8 + seg) * 2048 + n)) * 128;
    q[lane] = (bf16)n0; q[lane + 64] = (bf16)n1;
  } else if (seg == 8) {
    if (lane == 0) {
      float th = 0.1f * (float)n;
      float c = cosf(th), s_ = sinf(th);
      float r0 = n0 * c - n1 * s_, r1 = n1 * c + n0 * s_;
      n0 = r0; n1 = r1;
    }
    bf16* k = Ko + ((size_t)(b * 2048 + n)) * 128;
    k[lane] = (bf16)n0; k[lane + 64] = (bf16)n1;
  } else {
    float n2 = v2 * rs * vg[lane + 128];
    bf16* vp = Vo + ((size_t)(b * 2048 + n)) * 192;
    vp[lane] = (bf16)n0; vp[lane + 64] = (bf16)n1; vp[lane + 128] = (bf16)n2;
  }
}

// ---------------- V transpose: V bf16 [2][2048][192] -> Vt [2][192][2048]
__global__ __launch_bounds__(256) void vtrans(const bf16* __restrict__ V, bf16* __restrict__ Vt) {
  __shared__ bf16 t[32][33];
  int b = blockIdx.z;
  int j0 = blockIdx.x * 32, d0 = blockIdx.y * 32;
  int tx = threadIdx.x, ty = threadIdx.y;
#pragma unroll
  for (int k = 0; k < 4; ++k)
    t[ty + k * 8][tx] = V[((size_t)b * 2048 + j0 + ty + k * 8) * 192 + d0 + tx];
  __syncthreads();
#pragma unroll
  for (int k = 0; k < 4; ++k)
    Vt[((size_t)b * 192 + d0 + ty + k * 8) * 2048 + j0 + tx] = t[tx][ty + k * 8];
}

// ---------------- pairwise bias, all 8 layers batched:
// pn = p * rsqrt(mean(p^2)+eps) once; per layer: gelu(pn*g_d) @ Wb_d
// Bout layout [d][b][h][128][128] f32
__global__ void bias_pw8(const float* __restrict__ P, const float* __restrict__ G8,
                         const float* __restrict__ Wb8, float* __restrict__ Bout) {
  int j = blockIdx.x, i = blockIdx.y, b = blockIdx.z;
  int lane = threadIdx.x;
  const float* p = P + (((size_t)b * 128 + i) * 128 + j) * 128;
  float a0 = p[lane], a1 = p[lane + 64];
  float ss = wave_reduce_sum(a0 * a0 + a1 * a1);
  float rs = rsqrtf(ss * (1.f / 128.f) + EPSF);
  float pn0 = a0 * rs, pn1 = a1 * rs;
  __shared__ float gs[128];
  for (int d = 0; d < 8; ++d) {
    float x0 = pn0 * G8[d * 128 + lane], x1 = pn1 * G8[d * 128 + lane + 64];
    float g0 = 0.5f * x0 * (1.f + erff(x0 * 0.70710678118654752f));
    float g1 = 0.5f * x1 * (1.f + erff(x1 * 0.70710678118654752f));
    __syncthreads();
    gs[lane] = g0; gs[lane + 64] = g1;
    __syncthreads();
    int h = lane & 7;
    float acc = 0.f;
#pragma unroll
    for (int k = 0; k < 16; ++k) {
      int c = (lane >> 3) + k * 8;
      acc += gs[c] * Wb8[((size_t)d * 128 + c) * 8 + h];
    }
    acc += __shfl_xor(acc, 8, 64);
    acc += __shfl_xor(acc, 16, 64);
    acc += __shfl_xor(acc, 32, 64);
    if (lane < 8)
      Bout[((((size_t)d * 2 + b) * 8 + lane) * 128 + i) * 128 + j] = acc;
  }
}

// ---------------- attention (BI=64, full KV sweep, direct normalized output)
__global__ __launch_bounds__(256, 3) void attn_k(const bf16* __restrict__ Q,
                                                 const bf16* __restrict__ Kg,
                                                 const bf16* __restrict__ Vt,
                                                 const float* __restrict__ Bias,
                                                 bf16* __restrict__ Out) {
  __shared__ __align__(16) char Ks[64 * 256];  // [64 j][128 k] swz16
  __shared__ __align__(16) char Vs[192 * 128]; // [192 dv][64 j] swz8
  __shared__ __align__(16) char Ps[64 * 128];  // [64 i][64 j] bf16, swz8 by (row&7)
  __shared__ float BiasS[4 * 128];             // pre-scaled by 0.57707801
  int tid = threadIdx.x, lane = tid & 63, w = tid >> 6;
  int it = blockIdx.x, g = blockIdx.y, b = blockIdx.z;
  int i0 = it * 64;
  int l15 = lane & 15, l4 = lane >> 4;

  bf16x8 qf[4];
#pragma unroll
  for (int s = 0; s < 4; ++s)
    qf[s] = *(const bf16x8*)(Q + ((size_t)((b * 8 + g) * 2048 + i0 + w * 16 + l15)) * 128 + s * 32 + l4 * 8);

  if (tid < 128) {
    int r = tid >> 5, c = (tid & 31) * 4;
    float4 bv = *(const float4*)(Bias + ((size_t)((b * 8 + g) * 128) + (i0 >> 4) + r) * 128 + c);
    bv.x *= 0.57707801635558535f; bv.y *= 0.57707801635558535f;
    bv.z *= 0.57707801635558535f; bv.w *= 0.57707801635558535f;
    *(float4*)&BiasS[r * 128 + c] = bv;
  }

  f32x4 accO[12] = {};
  float lacc = 0.f;

  for (int jt = 0; jt < 32; ++jt) {
    int j0 = jt * 64;
#pragma unroll
    for (int r = 0; r < 4; ++r) {
      uint32_t o = (uint32_t)(r * 256 + tid) * 16;
      uint32_t row = o >> 8;
      uint32_t kb = ((o >> 4) & 15) ^ (row & 15);
      const bf16* src = Kg + ((size_t)b * 2048 + j0 + (int)row) * 128 + kb * 8;
      GLOAD_LDS16(src, Ks + (o & 0xFFFFFC00u));
    }
#pragma unroll
    for (int r = 0; r < 6; ++r) {
      uint32_t o = (uint32_t)(r * 256 + tid) * 16;
      uint32_t dv = o >> 7;
      uint32_t kb = ((o >> 4) & 7) ^ (dv & 7);
      const bf16* src = Vt + ((size_t)b * 192 + dv) * 2048 + j0 + kb * 8;
      GLOAD_LDS16(src, Vs + (o & 0xFFFFFC00u));
    }
    __syncthreads();

    // QK^T swapped: accS[n] = mfma(kf[n], qf[s])  (row=j, col=i=l15)
    f32x4 accS[4] = {};
#pragma unroll
    for (int s = 0; s < 4; ++s) {
      bf16x8 kf[4];
#pragma unroll
      for (int n = 0; n < 4; ++n) {
        uint32_t row = n * 16 + l15;
        uint32_t kb = (uint32_t)(s * 4 + l4);
        kf[n] = *(const bf16x8*)(Ks + row * 256 + (kb ^ (row & 15)) * 16);
      }
      __builtin_amdgcn_s_setprio(1);
#pragma unroll
      for (int n = 0; n < 4; ++n)
        accS[n] = __builtin_amdgcn_mfma_f32_16x16x32_bf16(kf[n], qf[s], accS[n], 0, 0, 0);
      __builtin_amdgcn_s_setprio(0);
    }

    // softclamp + exp -> packed b64 P-writes + per-lane sums
#pragma unroll
    for (int n = 0; n < 4; ++n) {
      float biaS = BiasS[w * 128 + jt * 4 + n];
      bf16x4 pk;
#pragma unroll
      for (int r = 0; r < 4; ++r) {
        float t1 = __builtin_fmaf(0.57707801635558535f, accS[n][r], biaS);
        float e1 = exp2f(t1);
        float rr = __builtin_amdgcn_rcpf(e1 + 1.0f);
        float pv = exp2f(-14.426950408889634f * rr);
        lacc += pv;
        pk[r] = (bf16)pv;
      }
      uint32_t prow = (uint32_t)(w * 16 + l15);
      uint32_t byteo = prow * 128 + (uint32_t)(n * 16 + l4 * 4) * 2;
      byteo ^= (prow & 7) << 4;
      *(bf16x4*)(Ps + byteo) = pk;
    }

    // PV swapped: accO[n] = mfma(vf, pa)  (row=dv, col=i)
#pragma unroll
    for (int s = 0; s < 2; ++s) {
      uint32_t prow = (uint32_t)(w * 16 + l15);
      uint32_t byteo = prow * 128 + (uint32_t)(s * 64 + l4 * 16);
      byteo ^= (prow & 7) << 4;
      bf16x8 pa = *(const bf16x8*)(Ps + byteo);
#pragma unroll
      for (int n = 0; n < 12; ++n) {
        uint32_t dvr = n * 16 + l15;
        uint32_t kb = (uint32_t)(s * 4 + l4);
        bf16x8 vf = *(const bf16x8*)(Vs + dvr * 128 + (kb ^ (dvr & 7)) * 16);
        __builtin_amdgcn_s_setprio(1);
        accO[n] = __builtin_amdgcn_mfma_f32_16x16x32_bf16(vf, pa, accO[n], 0, 0, 0);
        __builtin_amdgcn_s_setprio(0);
      }
    }
    __syncthreads();
  }

  lacc += __shfl_xor(lacc, 16, 64);
  lacc += __shfl_xor(lacc, 32, 64);
  float rl = __builtin_amdgcn_rcpf(lacc);

  {
    int i = i0 + w * 16 + l15;
#pragma unroll
    for (int n = 0; n < 12; ++n) {
      bf16x4 ok;
#pragma unroll
      for (int r = 0; r < 4; ++r) ok[r] = (bf16)(accO[n][r] * rl);
      int dv = n * 16 + l4 * 4;
      *(bf16x4*)(Out + ((size_t)(b * 2048 + i)) * 1536 + g * 192 + dv) = ok;
    }
  }
}

// =============================================================================
extern "C" void kernel_launch(void* const* d_in, const int* in_sizes, int n_in,
                              void* d_out, int out_size, void* d_ws, size_t ws_size,
                              hipStream_t stream) {
  (void)in_sizes; (void)n_in; (void)out_size;
  const float* x_in = (const float*)d_in[0];
  const float* pairwise = (const float*)d_in[1];
  const float* w_qkv = (const float*)d_in[2];
  const float* q_gamma = (const float*)d_in[3];
  const float* k_gamma = (const float*)d_in[4];
  const float* v_gamma = (const float*)d_in[5];
  const float* bias_gamma = (const float*)d_in[6];
  const float* w_bias = (const float*)d_in[7];
  const float* w_out = (const float*)d_in[8];
  const float* attn_pre = (const float*)d_in[9];
  const float* ff_pre = (const float*)d_in[10];
  const float* w_ff1 = (const float*)d_in[11];
  const float* b_ff1 = (const float*)d_in[12];
  const float* w_ff2 = (const float*)d_in[13];
  const float* b_ff2 = (const float*)d_in[14];

  char* p = (char*)d_ws;
  auto alloc = [&](size_t bytes) {
    char* r = p;
    p += (bytes + 255) & ~(size_t)255;
    return r;
  };
  bf16* wT_qkv = (bf16*)alloc(8ull * 1344 * 1536 * 2);
  bf16* wT_out = (bf16*)alloc(8ull * 1536 * 1536 * 2);
  bf16* wT_ff1 = (bf16*)alloc(8ull * 3072 * 1536 * 2);
  bf16* wT_ff2 = (bf16*)alloc(8ull * 1536 * 3072 * 2);
  float* x_ws = (float*)alloc(4096ull * 1536 * 4);
  bf16* xn = (bf16*)alloc(4096ull * 1536 * 2);
  bf16* qkvb = (bf16*)alloc(4096ull * 1344 * 2);
  bf16* qb = (bf16*)alloc(2ull * 8 * 2048 * 128 * 2);
  bf16* kb = (bf16*)alloc(2ull * 2048 * 128 * 2);
  bf16* vb = (bf16*)alloc(2ull * 2048 * 192 * 2);
  bf16* vtb = (bf16*)alloc(2ull * 192 * 2048 * 2);
  float* biasb8 = (float*)alloc(8ull * 2 * 8 * 128 * 128 * 4);
  bf16* attn_o = (bf16*)alloc(4096ull * 1536 * 2);
  bf16* hb = (bf16*)alloc(4096ull * 3072 * 2);
  if ((size_t)(p - (char*)d_ws) > ws_size) return;  // workspace too small

  // weight casts (transposed to [N][K] bf16)
  wcast_t<<<dim3(42, 48, 8), dim3(32, 8), 0, stream>>>(w_qkv, wT_qkv, 1536, 1344);
  wcast_t<<<dim3(48, 48, 8), dim3(32, 8), 0, stream>>>(w_out, wT_out, 1536, 1536);
  wcast_t<<<dim3(96, 48, 8), dim3(32, 8), 0, stream>>>(w_ff1, wT_ff1, 1536, 3072);
  wcast_t<<<dim3(48, 96, 8), dim3(32, 8), 0, stream>>>(w_ff2, wT_ff2, 3072, 1536);

  // all-layer pairwise bias (amortizes pairwise load + rmsnorm across 8 layers)
  bias_pw8<<<dim3(128, 128, 2), 64, 0, stream>>>(pairwise, bias_gamma, w_bias, biasb8);

  hipMemcpyAsync(x_ws, x_in, 4096ull * 1536 * 4, hipMemcpyDeviceToDevice, stream);

  for (int d = 0; d < 8; ++d) {
    const bf16* wq = wT_qkv + (size_t)d * 1344 * 1536;
    const bf16* wo = wT_out + (size_t)d * 1536 * 1536;
    const bf16* w1 = wT_ff1 + (size_t)d * 3072 * 1536;
    const bf16* w2 = wT_ff2 + (size_t)d * 1536 * 3072;

    rmsnorm_k<<<4096, 256, 0, stream>>>(x_ws, attn_pre + d * 1536, xn);
    gemm_bt64<5><<<dim3(11, 64), 256, 0, stream>>>(xn, wq, nullptr, qkvb, nullptr, 4096, 1344, 1536);
    qkv_post<<<dim3(1024, 10), 256, 0, stream>>>(qkvb, q_gamma + d * 128, k_gamma + d * 128,
                                                 v_gamma + d * 192, qb, kb, vb);
    vtrans<<<dim3(64, 6, 2), dim3(32, 8), 0, stream>>>(vb, vtb);
    attn_k<<<dim3(32, 8, 2), 256, 0, stream>>>(qb, kb, vtb,
                                               biasb8 + (size_t)d * 2 * 8 * 128 * 128, attn_o);
    gemm_bt64<2><<<dim3(12, 64), 256, 0, stream>>>(attn_o, wo, x_ws, nullptr, nullptr, 4096, 1536, 1536);
    rmsnorm_k<<<4096, 256, 0, stream>>>(x_ws, ff_pre + d * 1536, xn);
    gemm_bt<3><<<dim3(24, 32), 256, 0, stream>>>(xn, w1, nullptr, hb, b_ff1 + d * 3072, 4096, 3072, 1536);
    gemm_bt64<4><<<dim3(12, 64), 256, 0, stream>>>(hb, w2, x_ws, nullptr, b_ff2 + d * 1536, 4096, 1536, 3072);
  }

  hipMemcpyAsync(d_out, x_ws, 4096ull * 1536 * 4, hipMemcpyDeviceToDevice, stream);
}

// Round 16
// 2376.087 us; speedup vs baseline: 1.0337x; 1.0024x over previous
//
#include <hip/hip_runtime.h>

typedef __bf16 bf16;
typedef float f32x4 __attribute__((ext_vector_type(4)));
typedef __bf16 bf16x8 __attribute__((ext_vector_type(8)));
typedef __bf16 bf16x4 __attribute__((ext_vector_type(4)));

#define EPSF 1.1920928955078125e-07f

#define GLOAD_LDS16(gsrc, ldst) \
  __builtin_amdgcn_global_load_lds((const __attribute__((address_space(1))) void*)(gsrc), \
                                   (__attribute__((address_space(3))) void*)(ldst), 16, 0, 0)

__device__ __forceinline__ float wave_reduce_sum(float v) {
#pragma unroll
  for (int m = 1; m < 64; m <<= 1) v += __shfl_xor(v, m, 64);
  return v;
}

// ---------------- weight cast + transpose: src f32 [z][R][C] -> dst bf16 [z][C][R]
__global__ __launch_bounds__(256) void wcast_t(const float* __restrict__ src,
                                               bf16* __restrict__ dst, int R, int C) {
  __shared__ float t[32][33];
  int z = blockIdx.z;
  const float* s = src + (size_t)z * R * C;
  bf16* d = dst + (size_t)z * R * C;
  int c0 = blockIdx.x * 32, r0 = blockIdx.y * 32;
  int tx = threadIdx.x, ty = threadIdx.y;
#pragma unroll
  for (int k = 0; k < 4; ++k)
    t[ty + k * 8][tx] = s[(size_t)(r0 + ty + k * 8) * C + c0 + tx];
  __syncthreads();
#pragma unroll
  for (int k = 0; k < 4; ++k)
    d[(size_t)(c0 + ty + k * 8) * R + r0 + tx] = (bf16)t[tx][ty + k * 8];
}

// ---------------- RMSNorm: X f32 [rows][1536] * G -> O bf16
__global__ __launch_bounds__(256) void rmsnorm_k(const float* __restrict__ X,
                                                 const float* __restrict__ G,
                                                 bf16* __restrict__ O) {
  int row = blockIdx.x, tid = threadIdx.x, lane = tid & 63, w = tid >> 6;
  const float* x = X + (size_t)row * 1536;
  float v[6];
  float ss = 0.f;
#pragma unroll
  for (int k = 0; k < 6; ++k) { v[k] = x[tid + k * 256]; ss += v[k] * v[k]; }
  ss = wave_reduce_sum(ss);
  __shared__ float wsum[4];
  if (lane == 0) wsum[w] = ss;
  __syncthreads();
  ss = wsum[0] + wsum[1] + wsum[2] + wsum[3];
  float rs = rsqrtf(ss * (1.f / 1536.f) + EPSF);
  bf16* o = O + (size_t)row * 1536;
#pragma unroll
  for (int k = 0; k < 6; ++k) o[tid + k * 256] = (bf16)(v[k] * rs * G[tid + k * 256]);
}

// ---------------- GEMM 128x128, BK=64 (single-buffered, XCD-swizzled): ff1
// EPI: 2 = Cf += v; 3 = Cb = bf16(relu(v + bias)); 4 = Cf += v + bias; 5 = Cb = bf16(v)
template <int EPI>
__global__ __launch_bounds__(256, 3) void gemm_bt(const bf16* __restrict__ A,
                                                  const bf16* __restrict__ Bt,
                                                  float* __restrict__ Cf,
                                                  bf16* __restrict__ Cb,
                                                  const float* __restrict__ bias,
                                                  int M, int N, int K) {
  __shared__ __align__(16) char As[128 * 128];
  __shared__ __align__(16) char Bs[128 * 128];
  const int tid = threadIdx.x;
  const int lane = tid & 63, l15 = lane & 15, l4 = lane >> 4;
  const int w = tid >> 6;
  const int nwg = gridDim.x * gridDim.y;
  const int bid = blockIdx.y * gridDim.x + blockIdx.x;
  const int cpx = nwg >> 3;
  const int swz = (bid & 7) * cpx + (bid >> 3);
  const int rm = (swz / gridDim.x) * 128;
  const int cn = (swz % gridDim.x) * 128;
  const int wm = (w >> 1) * 64, wn = (w & 1) * 64;
  f32x4 acc[4][4] = {};

  for (int kk = 0; kk < K; kk += 64) {
#pragma unroll
    for (int r = 0; r < 4; ++r) {
      uint32_t o = (uint32_t)(r * 256 + tid) * 16;
      uint32_t row = o >> 7;
      uint32_t kb = ((o >> 4) & 7) ^ (row & 7);
      const bf16* src = A + (size_t)(rm + (int)row) * K + kk + kb * 8;
      GLOAD_LDS16(src, As + (o & 0xFFFFFC00u));
    }
#pragma unroll
    for (int r = 0; r < 4; ++r) {
      uint32_t o = (uint32_t)(r * 256 + tid) * 16;
      uint32_t row = o >> 7;
      uint32_t kb = ((o >> 4) & 7) ^ (row & 7);
      int nrow = cn + (int)row;
      if (nrow >= N) nrow = N - 1;
      const bf16* src = Bt + (size_t)nrow * K + kk + kb * 8;
      GLOAD_LDS16(src, Bs + (o & 0xFFFFFC00u));
    }
    __syncthreads();
#pragma unroll
    for (int s = 0; s < 2; ++s) {
      bf16x8 a[4], b[4];
#pragma unroll
      for (int m = 0; m < 4; ++m) {
        uint32_t row = wm + m * 16 + l15;
        uint32_t kb = (uint32_t)(s * 4 + l4);
        a[m] = *(const bf16x8*)(As + row * 128 + (kb ^ (row & 7)) * 16);
      }
#pragma unroll
      for (int n = 0; n < 4; ++n) {
        uint32_t row = wn + n * 16 + l15;
        uint32_t kb = (uint32_t)(s * 4 + l4);
        b[n] = *(const bf16x8*)(Bs + row * 128 + (kb ^ (row & 7)) * 16);
      }
      __builtin_amdgcn_s_setprio(1);
#pragma unroll
      for (int m = 0; m < 4; ++m)
#pragma unroll
        for (int n = 0; n < 4; ++n)
          acc[m][n] = __builtin_amdgcn_mfma_f32_16x16x32_bf16(a[m], b[n], acc[m][n], 0, 0, 0);
      __builtin_amdgcn_s_setprio(0);
    }
    __syncthreads();
  }

#pragma unroll
  for (int m = 0; m < 4; ++m)
#pragma unroll
    for (int n = 0; n < 4; ++n)
#pragma unroll
      for (int r = 0; r < 4; ++r) {
        int row = rm + wm + m * 16 + l4 * 4 + r;
        int col = cn + wn + n * 16 + l15;
        if (col < N) {
          float v = acc[m][n][r];
          size_t idx = (size_t)row * N + col;
          if constexpr (EPI == 2) {
            Cf[idx] += v;
          } else if constexpr (EPI == 3) {
            float tv = v + bias[col];
            Cb[idx] = (bf16)(tv > 0.f ? tv : 0.f);
          } else if constexpr (EPI == 4) {
            Cf[idx] += v + bias[col];
          } else if constexpr (EPI == 5) {
            Cb[idx] = (bf16)v;
          }
        }
      }
}

// ---------------- GEMM 64x128 tile, BK=128 (LDS 48KB, 3 blocks/CU): qkv / out / ff2
// Rows are 256B (128 bf16); swz16 staging pattern (identical to attn Ks layout).
template <int EPI>
__global__ __launch_bounds__(256, 3) void gemm_bt64(const bf16* __restrict__ A,
                                                    const bf16* __restrict__ Bt,
                                                    float* __restrict__ Cf,
                                                    bf16* __restrict__ Cb,
                                                    const float* __restrict__ bias,
                                                    int M, int N, int K) {
  __shared__ __align__(16) char As[64 * 256];   // [64 m][128 k] swz16
  __shared__ __align__(16) char Bs[128 * 256];  // [128 n][128 k] swz16
  const int tid = threadIdx.x;
  const int lane = tid & 63, l15 = lane & 15, l4 = lane >> 4;
  const int w = tid >> 6;
  const int nwg = gridDim.x * gridDim.y;
  const int bid = blockIdx.y * gridDim.x + blockIdx.x;
  const int cpx = nwg >> 3;
  const int swz = (bid & 7) * cpx + (bid >> 3);
  const int rm = (swz / gridDim.x) * 64;
  const int cn = (swz % gridDim.x) * 128;
  const int wm = (w >> 1) * 32, wn = (w & 1) * 64;
  f32x4 acc[2][4] = {};

  for (int kk = 0; kk < K; kk += 128) {
#pragma unroll
    for (int r = 0; r < 4; ++r) {
      uint32_t o = (uint32_t)(r * 256 + tid) * 16;
      uint32_t row = o >> 8;
      uint32_t kb = ((o >> 4) & 15) ^ (row & 15);
      const bf16* src = A + (size_t)(rm + (int)row) * K + kk + kb * 8;
      GLOAD_LDS16(src, As + (o & 0xFFFFF800u) + ((o & 0x7F0u)));
    }
#pragma unroll
    for (int r = 0; r < 8; ++r) {
      uint32_t o = (uint32_t)(r * 256 + tid) * 16;
      uint32_t row = o >> 8;
      uint32_t kb = ((o >> 4) & 15) ^ (row & 15);
      int nrow = cn + (int)row;
      if (nrow >= N) nrow = N - 1;
      const bf16* src = Bt + (size_t)nrow * K + kk + kb * 8;
      GLOAD_LDS16(src, Bs + (o & 0xFFFFF800u) + ((o & 0x7F0u)));
    }
    __syncthreads();
#pragma unroll
    for (int s = 0; s < 4; ++s) {
      bf16x8 a[2], b[4];
#pragma unroll
      for (int m = 0; m < 2; ++m) {
        uint32_t row = wm + m * 16 + l15;
        uint32_t kb = (uint32_t)(s * 4 + l4);
        a[m] = *(const bf16x8*)(As + row * 256 + ((kb ^ (row & 15)) * 16));
      }
#pragma unroll
      for (int n = 0; n < 4; ++n) {
        uint32_t row = wn + n * 16 + l15;
        uint32_t kb = (uint32_t)(s * 4 + l4);
        b[n] = *(const bf16x8*)(Bs + row * 256 + ((kb ^ (row & 15)) * 16));
      }
      __builtin_amdgcn_s_setprio(1);
#pragma unroll
      for (int m = 0; m < 2; ++m)
#pragma unroll
        for (int n = 0; n < 4; ++n)
          acc[m][n] = __builtin_amdgcn_mfma_f32_16x16x32_bf16(a[m], b[n], acc[m][n], 0, 0, 0);
      __builtin_amdgcn_s_setprio(0);
    }
    __syncthreads();
  }

#pragma unroll
  for (int m = 0; m < 2; ++m)
#pragma unroll
    for (int n = 0; n < 4; ++n)
#pragma unroll
      for (int r = 0; r < 4; ++r) {
        int row = rm + wm + m * 16 + l4 * 4 + r;
        int col = cn + wn + n * 16 + l15;
        if (col < N) {
          float v = acc[m][n][r];
          size_t idx = (size_t)row * N + col;
          if constexpr (EPI == 2) {
            Cf[idx] += v;
          } else if constexpr (EPI == 3) {
            float tv = v + bias[col];
            Cb[idx] = (bf16)(tv > 0.f ? tv : 0.f);
          } else if constexpr (EPI == 4) {
            Cf[idx] += v + bias[col];
          } else if constexpr (EPI == 5) {
            Cb[idx] = (bf16)v;
          }
        }
      }
}

// ---------------- QKV postprocess (4 tokens/block): per (token, segment) RMSNorm (+scale+rope)
__global__ __launch_bounds__(256) void qkv_post(const bf16* __restrict__ qkv,
                                                const float* __restrict__ qg,
                                                const float* __restrict__ kg,
                                                const float* __restrict__ vg,
                                                bf16* __restrict__ Qo, bf16* __restrict__ Ko,
                                                bf16* __restrict__ Vo) {
  int lane = threadIdx.x & 63, wv = threadIdx.x >> 6;
  int t = blockIdx.x * 4 + wv, seg = blockIdx.y;
  int b = t >> 11, n = t & 2047;
  const bf16* base;
  const float* gamma;
  int len;
  if (seg < 8) { base = qkv + (size_t)t * 1344 + seg * 128; gamma = qg; len = 128; }
  else if (seg == 8) { base = qkv + (size_t)t * 1344 + 1024; gamma = kg; len = 128; }
  else { base = qkv + (size_t)t * 1344 + 1152; gamma = vg; len = 192; }
  float v0 = (float)base[lane], v1 = (float)base[lane + 64];
  float v2 = (len == 192) ? (float)base[lane + 128] : 0.f;
  float ss = wave_reduce_sum(v0 * v0 + v1 * v1 + v2 * v2);
  float rs = rsqrtf(ss / (float)len + EPSF);
  float n0 = v0 * rs * gamma[lane];
  float n1 = v1 * rs * gamma[lane + 64];
  if (seg < 8) {
    n0 *= 0.125f; n1 *= 0.125f;
    if (lane == 0) {
      float th = 0.1f * (float)n;
      float c = cosf(th), s_ = sinf(th);
      float r0 = n0 * c - n1 * s_, r1 = n1 * c + n0 * s_;
      n0 = r0; n1 = r1;
    }
    bf16* q = Qo + ((size_t)((b * 8 + seg) * 2048 + n)) * 128;
    q[lane] = (bf16)n0; q[lane + 64] = (bf16)n1;
  } else if (seg == 8) {
    if (lane == 0) {
      float th = 0.1f * (float)n;
      float c = cosf(th), s_ = sinf(th);
      float r0 = n0 * c - n1 * s_, r1 = n1 * c + n0 * s_;
      n0 = r0; n1 = r1;
    }
    bf16* k = Ko + ((size_t)(b * 2048 + n)) * 128;
    k[lane] = (bf16)n0; k[lane + 64] = (bf16)n1;
  } else {
    float n2 = v2 * rs * vg[lane + 128];
    bf16* vp = Vo + ((size_t)(b * 2048 + n)) * 192;
    vp[lane] = (bf16)n0; vp[lane + 64] = (bf16)n1; vp[lane + 128] = (bf16)n2;
  }
}

// ---------------- V transpose: V bf16 [2][2048][192] -> Vt [2][192][2048]
__global__ __launch_bounds__(256) void vtrans(const bf16* __restrict__ V, bf16* __restrict__ Vt) {
  __shared__ bf16 t[32][33];
  int b = blockIdx.z;
  int j0 = blockIdx.x * 32, d0 = blockIdx.y * 32;
  int tx = threadIdx.x, ty = threadIdx.y;
#pragma unroll
  for (int k = 0; k < 4; ++k)
    t[ty + k * 8][tx] = V[((size_t)b * 2048 + j0 + ty + k * 8) * 192 + d0 + tx];
  __syncthreads();
#pragma unroll
  for (int k = 0; k < 4; ++k)
    Vt[((size_t)b * 192 + d0 + ty + k * 8) * 2048 + j0 + tx] = t[tx][ty + k * 8];
}

// ---------------- pairwise bias, all 8 layers batched:
// pn = p * rsqrt(mean(p^2)+eps) once; per layer: gelu(pn*g_d) @ Wb_d
// Bout layout [d][b][h][128][128] f32
__global__ void bias_pw8(const float* __restrict__ P, const float* __restrict__ G8,
                         const float* __restrict__ Wb8, float* __restrict__ Bout) {
  int j = blockIdx.x, i = blockIdx.y, b = blockIdx.z;
  int lane = threadIdx.x;
  const float* p = P + (((size_t)b * 128 + i) * 128 + j) * 128;
  float a0 = p[lane], a1 = p[lane + 64];
  float ss = wave_reduce_sum(a0 * a0 + a1 * a1);
  float rs = rsqrtf(ss * (1.f / 128.f) + EPSF);
  float pn0 = a0 * rs, pn1 = a1 * rs;
  __shared__ float gs[128];
  for (int d = 0; d < 8; ++d) {
    float x0 = pn0 * G8[d * 128 + lane], x1 = pn1 * G8[d * 128 + lane + 64];
    float g0 = 0.5f * x0 * (1.f + erff(x0 * 0.70710678118654752f));
    float g1 = 0.5f * x1 * (1.f + erff(x1 * 0.70710678118654752f));
    __syncthreads();
    gs[lane] = g0; gs[lane + 64] = g1;
    __syncthreads();
    int h = lane & 7;
    float acc = 0.f;
#pragma unroll
    for (int k = 0; k < 16; ++k) {
      int c = (lane >> 3) + k * 8;
      acc += gs[c] * Wb8[((size_t)d * 128 + c) * 8 + h];
    }
    acc += __shfl_xor(acc, 8, 64);
    acc += __shfl_xor(acc, 16, 64);
    acc += __shfl_xor(acc, 32, 64);
    if (lane < 8)
      Bout[((((size_t)d * 2 + b) * 8 + lane) * 128 + i) * 128 + j] = acc;
  }
}

// ---------------- attention (BI=64, full KV sweep, PV dv-split across waves)
// QK^T/softmax: wave w owns q-rows w*16..+15 (writes its P rows).
// PV: wave w owns dv range w*48..+47 for ALL 64 q-rows (reads all P rows; needs barrier).
// Row sums shared via LDS for the final normalization.
__global__ __launch_bounds__(256, 3) void attn_k(const bf16* __restrict__ Q,
                                                 const bf16* __restrict__ Kg,
                                                 const bf16* __restrict__ Vt,
                                                 const float* __restrict__ Bias,
                                                 bf16* __restrict__ Out) {
  __shared__ __align__(16) char Ks[64 * 256];  // [64 j][128 k] swz16
  __shared__ __align__(16) char Vs[192 * 128]; // [192 dv][64 j] swz8
  __shared__ __align__(16) char Ps[64 * 128];  // [64 i][64 j] bf16, swz8 by (row&7)
  __shared__ float BiasS[4 * 128];             // pre-scaled by 0.57707801
  __shared__ float RowSum[64];
  int tid = threadIdx.x, lane = tid & 63, w = tid >> 6;
  int it = blockIdx.x, g = blockIdx.y, b = blockIdx.z;
  int i0 = it * 64;
  int l15 = lane & 15, l4 = lane >> 4;

  bf16x8 qf[4];
#pragma unroll
  for (int s = 0; s < 4; ++s)
    qf[s] = *(const bf16x8*)(Q + ((size_t)((b * 8 + g) * 2048 + i0 + w * 16 + l15)) * 128 + s * 32 + l4 * 8);

  if (tid < 128) {
    int r = tid >> 5, c = (tid & 31) * 4;
    float4 bv = *(const float4*)(Bias + ((size_t)((b * 8 + g) * 128) + (i0 >> 4) + r) * 128 + c);
    bv.x *= 0.57707801635558535f; bv.y *= 0.57707801635558535f;
    bv.z *= 0.57707801635558535f; bv.w *= 0.57707801635558535f;
    *(float4*)&BiasS[r * 128 + c] = bv;
  }

  f32x4 accO[4][3] = {};  // [q-row group m][dv tile n in this wave's 48-range]
  float lacc = 0.f;

  for (int jt = 0; jt < 32; ++jt) {
    int j0 = jt * 64;
#pragma unroll
    for (int r = 0; r < 4; ++r) {
      uint32_t o = (uint32_t)(r * 256 + tid) * 16;
      uint32_t row = o >> 8;
      uint32_t kb = ((o >> 4) & 15) ^ (row & 15);
      const bf16* src = Kg + ((size_t)b * 2048 + j0 + (int)row) * 128 + kb * 8;
      GLOAD_LDS16(src, Ks + (o & 0xFFFFFC00u));
    }
#pragma unroll
    for (int r = 0; r < 6; ++r) {
      uint32_t o = (uint32_t)(r * 256 + tid) * 16;
      uint32_t dv = o >> 7;
      uint32_t kb = ((o >> 4) & 7) ^ (dv & 7);
      const bf16* src = Vt + ((size_t)b * 192 + dv) * 2048 + j0 + kb * 8;
      GLOAD_LDS16(src, Vs + (o & 0xFFFFFC00u));
    }
    __syncthreads();

    // QK^T swapped: accS[n] = mfma(kf[n], qf[s])  (row=j, col=i=l15)
    f32x4 accS[4] = {};
#pragma unroll
    for (int s = 0; s < 4; ++s) {
      bf16x8 kf[4];
#pragma unroll
      for (int n = 0; n < 4; ++n) {
        uint32_t row = n * 16 + l15;
        uint32_t kb = (uint32_t)(s * 4 + l4);
        kf[n] = *(const bf16x8*)(Ks + row * 256 + (kb ^ (row & 15)) * 16);
      }
      __builtin_amdgcn_s_setprio(1);
#pragma unroll
      for (int n = 0; n < 4; ++n)
        accS[n] = __builtin_amdgcn_mfma_f32_16x16x32_bf16(kf[n], qf[s], accS[n], 0, 0, 0);
      __builtin_amdgcn_s_setprio(0);
    }

    // softclamp + exp -> packed b64 P-writes (wave's own rows) + per-lane sums
#pragma unroll
    for (int n = 0; n < 4; ++n) {
      float biaS = BiasS[w * 128 + jt * 4 + n];
      bf16x4 pk;
#pragma unroll
      for (int r = 0; r < 4; ++r) {
        float t1 = __builtin_fmaf(0.57707801635558535f, accS[n][r], biaS);
        float e1 = exp2f(t1);
        float rr = __builtin_amdgcn_rcpf(e1 + 1.0f);
        float pv = exp2f(-14.426950408889634f * rr);
        lacc += pv;
        pk[r] = (bf16)pv;
      }
      uint32_t prow = (uint32_t)(w * 16 + l15);
      uint32_t byteo = prow * 128 + (uint32_t)(n * 16 + l4 * 4) * 2;
      byteo ^= (prow & 7) << 4;
      *(bf16x4*)(Ps + byteo) = pk;
    }
    __syncthreads();  // P now complete for all 64 rows

    // PV dv-split: wave w computes accO over all 64 q-rows x its 48 dv
#pragma unroll
    for (int s = 0; s < 2; ++s) {
      bf16x8 pa[4];
#pragma unroll
      for (int m = 0; m < 4; ++m) {
        uint32_t prow = (uint32_t)(m * 16 + l15);
        uint32_t byteo = prow * 128 + (uint32_t)(s * 64 + l4 * 16);
        byteo ^= (prow & 7) << 4;
        pa[m] = *(const bf16x8*)(Ps + byteo);
      }
#pragma unroll
      for (int n = 0; n < 3; ++n) {
        uint32_t dvr = (uint32_t)(w * 48 + n * 16 + l15);
        uint32_t kb = (uint32_t)(s * 4 + l4);
        bf16x8 vf = *(const bf16x8*)(Vs + dvr * 128 + (kb ^ (dvr & 7)) * 16);
        __builtin_amdgcn_s_setprio(1);
#pragma unroll
        for (int m = 0; m < 4; ++m)
          accO[m][n] = __builtin_amdgcn_mfma_f32_16x16x32_bf16(vf, pa[m], accO[m][n], 0, 0, 0);
        __builtin_amdgcn_s_setprio(0);
      }
    }
    __syncthreads();
  }

  // row sums (wave's own 16 rows) -> LDS so all waves can normalize any row
  lacc += __shfl_xor(lacc, 16, 64);
  lacc += __shfl_xor(lacc, 32, 64);
  if (l4 == 0) RowSum[w * 16 + l15] = lacc;
  __syncthreads();

  // normalized output: accO[m][n][r] = O[dv = w*48+n*16+l4*4+r][i = i0+m*16+l15]
#pragma unroll
  for (int m = 0; m < 4; ++m) {
    int i = i0 + m * 16 + l15;
    float rl = __builtin_amdgcn_rcpf(RowSum[m * 16 + l15]);
#pragma unroll
    for (int n = 0; n < 3; ++n) {
      bf16x4 ok;
#pragma unroll
      for (int r = 0; r < 4; ++r) ok[r] = (bf16)(accO[m][n][r] * rl);
      int dv = w * 48 + n * 16 + l4 * 4;
      *(bf16x4*)(Out + ((size_t)(b * 2048 + i)) * 1536 + g * 192 + dv) = ok;
    }
  }
}

// =============================================================================
extern "C" void kernel_launch(void* const* d_in, const int* in_sizes, int n_in,
                              void* d_out, int out_size, void* d_ws, size_t ws_size,
                              hipStream_t stream) {
  (void)in_sizes; (void)n_in; (void)out_size;
  const float* x_in = (const float*)d_in[0];
  const float* pairwise = (const float*)d_in[1];
  const float* w_qkv = (const float*)d_in[2];
  const float* q_gamma = (const float*)d_in[3];
  const float* k_gamma = (const float*)d_in[4];
  const float* v_gamma = (const float*)d_in[5];
  const float* bias_gamma = (const float*)d_in[6];
  const float* w_bias = (const float*)d_in[7];
  const float* w_out = (const float*)d_in[8];
  const float* attn_pre = (const float*)d_in[9];
  const float* ff_pre = (const float*)d_in[10];
  const float* w_ff1 = (const float*)d_in[11];
  const float* b_ff1 = (const float*)d_in[12];
  const float* w_ff2 = (const float*)d_in[13];
  const float* b_ff2 = (const float*)d_in[14];

  char* p = (char*)d_ws;
  auto alloc = [&](size_t bytes) {
    char* r = p;
    p += (bytes + 255) & ~(size_t)255;
    return r;
  };
  bf16* wT_qkv = (bf16*)alloc(8ull * 1344 * 1536 * 2);
  bf16* wT_out = (bf16*)alloc(8ull * 1536 * 1536 * 2);
  bf16* wT_ff1 = (bf16*)alloc(8ull * 3072 * 1536 * 2);
  bf16* wT_ff2 = (bf16*)alloc(8ull * 1536 * 3072 * 2);
  float* x_ws = (float*)alloc(4096ull * 1536 * 4);
  bf16* xn = (bf16*)alloc(4096ull * 1536 * 2);
  bf16* qkvb = (bf16*)alloc(4096ull * 1344 * 2);
  bf16* qb = (bf16*)alloc(2ull * 8 * 2048 * 128 * 2);
  bf16* kb = (bf16*)alloc(2ull * 2048 * 128 * 2);
  bf16* vb = (bf16*)alloc(2ull * 2048 * 192 * 2);
  bf16* vtb = (bf16*)alloc(2ull * 192 * 2048 * 2);
  float* biasb8 = (float*)alloc(8ull * 2 * 8 * 128 * 128 * 4);
  bf16* attn_o = (bf16*)alloc(4096ull * 1536 * 2);
  bf16* hb = (bf16*)alloc(4096ull * 3072 * 2);
  if ((size_t)(p - (char*)d_ws) > ws_size) return;  // workspace too small

  // weight casts (transposed to [N][K] bf16)
  wcast_t<<<dim3(42, 48, 8), dim3(32, 8), 0, stream>>>(w_qkv, wT_qkv, 1536, 1344);
  wcast_t<<<dim3(48, 48, 8), dim3(32, 8), 0, stream>>>(w_out, wT_out, 1536, 1536);
  wcast_t<<<dim3(96, 48, 8), dim3(32, 8), 0, stream>>>(w_ff1, wT_ff1, 1536, 3072);
  wcast_t<<<dim3(48, 96, 8), dim3(32, 8), 0, stream>>>(w_ff2, wT_ff2, 3072, 1536);

  // all-layer pairwise bias (amortizes pairwise load + rmsnorm across 8 layers)
  bias_pw8<<<dim3(128, 128, 2), 64, 0, stream>>>(pairwise, bias_gamma, w_bias, biasb8);

  hipMemcpyAsync(x_ws, x_in, 4096ull * 1536 * 4, hipMemcpyDeviceToDevice, stream);

  for (int d = 0; d < 8; ++d) {
    const bf16* wq = wT_qkv + (size_t)d * 1344 * 1536;
    const bf16* wo = wT_out + (size_t)d * 1536 * 1536;
    const bf16* w1 = wT_ff1 + (size_t)d * 3072 * 1536;
    const bf16* w2 = wT_ff2 + (size_t)d * 1536 * 3072;

    rmsnorm_k<<<4096, 256, 0, stream>>>(x_ws, attn_pre + d * 1536, xn);
    gemm_bt64<5><<<dim3(11, 64), 256, 0, stream>>>(xn, wq, nullptr, qkvb, nullptr, 4096, 1344, 1536);
    qkv_post<<<dim3(1024, 10), 256, 0, stream>>>(qkvb, q_gamma + d * 128, k_gamma + d * 128,
                                                 v_gamma + d * 192, qb, kb, vb);
    vtrans<<<dim3(64, 6, 2), dim3(32, 8), 0, stream>>>(vb, vtb);
    attn_k<<<dim3(32, 8, 2), 256, 0, stream>>>(qb, kb, vtb,
                                               biasb8 + (size_t)d * 2 * 8 * 128 * 128, attn_o);
    gemm_bt64<2><<<dim3(12, 64), 256, 0, stream>>>(attn_o, wo, x_ws, nullptr, nullptr, 4096, 1536, 1536);
    rmsnorm_k<<<4096, 256, 0, stream>>>(x_ws, ff_pre + d * 1536, xn);
    gemm_bt<3><<<dim3(24, 32), 256, 0, stream>>>(xn, w1, nullptr, hb, b_ff1 + d * 3072, 4096, 3072, 1536);
    gemm_bt64<4><<<dim3(12, 64), 256, 0, stream>>>(hb, w2, x_ws, nullptr, b_ff2 + d * 1536, 4096, 1536, 3072);
  }

  hipMemcpyAsync(d_out, x_ws, 4096ull * 1536 * 4, hipMemcpyDeviceToDevice, stream);
}

// Round 17
// 2346.450 us; speedup vs baseline: 1.0467x; 1.0126x over previous
//
#include <hip/hip_runtime.h>

typedef __bf16 bf16;
typedef float f32x4 __attribute__((ext_vector_type(4)));
typedef __bf16 bf16x8 __attribute__((ext_vector_type(8)));
typedef __bf16 bf16x4 __attribute__((ext_vector_type(4)));

#define EPSF 1.1920928955078125e-07f

#define GLOAD_LDS16(gsrc, ldst) \
  __builtin_amdgcn_global_load_lds((const __attribute__((address_space(1))) void*)(gsrc), \
                                   (__attribute__((address_space(3))) void*)(ldst), 16, 0, 0)

__device__ __forceinline__ float wave_reduce_sum(float v) {
#pragma unroll
  for (int m = 1; m < 64; m <<= 1) v += __shfl_xor(v, m, 64);
  return v;
}

// ---------------- weight cast + transpose: src f32 [z][R][C] -> dst bf16 [z][C][R]
__global__ __launch_bounds__(256) void wcast_t(const float* __restrict__ src,
                                               bf16* __restrict__ dst, int R, int C) {
  __shared__ float t[32][33];
  int z = blockIdx.z;
  const float* s = src + (size_t)z * R * C;
  bf16* d = dst + (size_t)z * R * C;
  int c0 = blockIdx.x * 32, r0 = blockIdx.y * 32;
  int tx = threadIdx.x, ty = threadIdx.y;
#pragma unroll
  for (int k = 0; k < 4; ++k)
    t[ty + k * 8][tx] = s[(size_t)(r0 + ty + k * 8) * C + c0 + tx];
  __syncthreads();
#pragma unroll
  for (int k = 0; k < 4; ++k)
    d[(size_t)(c0 + ty + k * 8) * R + r0 + tx] = (bf16)t[tx][ty + k * 8];
}

// ---------------- RMSNorm (wave-per-row, no barriers): X f32 [rows][1536] * G -> O bf16
__global__ __launch_bounds__(256) void rmsnorm_k(const float* __restrict__ X,
                                                 const float* __restrict__ G,
                                                 bf16* __restrict__ O) {
  int lane = threadIdx.x & 63, w = threadIdx.x >> 6;
  int row = blockIdx.x * 4 + w;
  const float* x = X + (size_t)row * 1536;
  float4 v[6];
  float ss = 0.f;
#pragma unroll
  for (int j = 0; j < 6; ++j) {
    v[j] = *(const float4*)(x + lane * 4 + j * 256);
    ss += v[j].x * v[j].x + v[j].y * v[j].y + v[j].z * v[j].z + v[j].w * v[j].w;
  }
  ss = wave_reduce_sum(ss);
  float rs = rsqrtf(ss * (1.f / 1536.f) + EPSF);
  bf16* o = O + (size_t)row * 1536;
#pragma unroll
  for (int j = 0; j < 6; ++j) {
    float4 g = *(const float4*)(G + lane * 4 + j * 256);
    bf16x4 ob;
    ob[0] = (bf16)(v[j].x * rs * g.x);
    ob[1] = (bf16)(v[j].y * rs * g.y);
    ob[2] = (bf16)(v[j].z * rs * g.z);
    ob[3] = (bf16)(v[j].w * rs * g.w);
    *(bf16x4*)(o + lane * 4 + j * 256) = ob;
  }
}

// ---------------- GEMM 128x128, BK=64 (single-buffered, XCD-swizzled): ff1
// EPI: 2 = Cf += v; 3 = Cb = bf16(relu(v + bias)); 4 = Cf += v + bias; 5 = Cb = bf16(v)
template <int EPI>
__global__ __launch_bounds__(256, 3) void gemm_bt(const bf16* __restrict__ A,
                                                  const bf16* __restrict__ Bt,
                                                  float* __restrict__ Cf,
                                                  bf16* __restrict__ Cb,
                                                  const float* __restrict__ bias,
                                                  int M, int N, int K) {
  __shared__ __align__(16) char As[128 * 128];
  __shared__ __align__(16) char Bs[128 * 128];
  const int tid = threadIdx.x;
  const int lane = tid & 63, l15 = lane & 15, l4 = lane >> 4;
  const int w = tid >> 6;
  const int nwg = gridDim.x * gridDim.y;
  const int bid = blockIdx.y * gridDim.x + blockIdx.x;
  const int cpx = nwg >> 3;
  const int swz = (bid & 7) * cpx + (bid >> 3);
  const int rm = (swz / gridDim.x) * 128;
  const int cn = (swz % gridDim.x) * 128;
  const int wm = (w >> 1) * 64, wn = (w & 1) * 64;
  f32x4 acc[4][4] = {};

  for (int kk = 0; kk < K; kk += 64) {
#pragma unroll
    for (int r = 0; r < 4; ++r) {
      uint32_t o = (uint32_t)(r * 256 + tid) * 16;
      uint32_t row = o >> 7;
      uint32_t kb = ((o >> 4) & 7) ^ (row & 7);
      const bf16* src = A + (size_t)(rm + (int)row) * K + kk + kb * 8;
      GLOAD_LDS16(src, As + (o & 0xFFFFFC00u));
    }
#pragma unroll
    for (int r = 0; r < 4; ++r) {
      uint32_t o = (uint32_t)(r * 256 + tid) * 16;
      uint32_t row = o >> 7;
      uint32_t kb = ((o >> 4) & 7) ^ (row & 7);
      int nrow = cn + (int)row;
      if (nrow >= N) nrow = N - 1;
      const bf16* src = Bt + (size_t)nrow * K + kk + kb * 8;
      GLOAD_LDS16(src, Bs + (o & 0xFFFFFC00u));
    }
    __syncthreads();
#pragma unroll
    for (int s = 0; s < 2; ++s) {
      bf16x8 a[4], b[4];
#pragma unroll
      for (int m = 0; m < 4; ++m) {
        uint32_t row = wm + m * 16 + l15;
        uint32_t kb = (uint32_t)(s * 4 + l4);
        a[m] = *(const bf16x8*)(As + row * 128 + (kb ^ (row & 7)) * 16);
      }
#pragma unroll
      for (int n = 0; n < 4; ++n) {
        uint32_t row = wn + n * 16 + l15;
        uint32_t kb = (uint32_t)(s * 4 + l4);
        b[n] = *(const bf16x8*)(Bs + row * 128 + (kb ^ (row & 7)) * 16);
      }
      __builtin_amdgcn_s_setprio(1);
#pragma unroll
      for (int m = 0; m < 4; ++m)
#pragma unroll
        for (int n = 0; n < 4; ++n)
          acc[m][n] = __builtin_amdgcn_mfma_f32_16x16x32_bf16(a[m], b[n], acc[m][n], 0, 0, 0);
      __builtin_amdgcn_s_setprio(0);
    }
    __syncthreads();
  }

#pragma unroll
  for (int m = 0; m < 4; ++m)
#pragma unroll
    for (int n = 0; n < 4; ++n)
#pragma unroll
      for (int r = 0; r < 4; ++r) {
        int row = rm + wm + m * 16 + l4 * 4 + r;
        int col = cn + wn + n * 16 + l15;
        if (col < N) {
          float v = acc[m][n][r];
          size_t idx = (size_t)row * N + col;
          if constexpr (EPI == 2) {
            Cf[idx] += v;
          } else if constexpr (EPI == 3) {
            float tv = v + bias[col];
            Cb[idx] = (bf16)(tv > 0.f ? tv : 0.f);
          } else if constexpr (EPI == 4) {
            Cf[idx] += v + bias[col];
          } else if constexpr (EPI == 5) {
            Cb[idx] = (bf16)v;
          }
        }
      }
}

// ---------------- GEMM 64x128 tile, BK=128 (LDS 48KB, 3 blocks/CU): qkv / out / ff2
// EPI: 2 = Cf += v; 4 = Cf += v + bias; 5 = Cb = bf16(v); 6 = Cf2 = Cf + v + bias
template <int EPI>
__global__ __launch_bounds__(256, 3) void gemm_bt64(const bf16* __restrict__ A,
                                                    const bf16* __restrict__ Bt,
                                                    float* __restrict__ Cf,
                                                    bf16* __restrict__ Cb,
                                                    const float* __restrict__ bias,
                                                    float* __restrict__ Cf2,
                                                    int M, int N, int K) {
  __shared__ __align__(16) char As[64 * 256];   // [64 m][128 k] swz16
  __shared__ __align__(16) char Bs[128 * 256];  // [128 n][128 k] swz16
  const int tid = threadIdx.x;
  const int lane = tid & 63, l15 = lane & 15, l4 = lane >> 4;
  const int w = tid >> 6;
  const int nwg = gridDim.x * gridDim.y;
  const int bid = blockIdx.y * gridDim.x + blockIdx.x;
  const int cpx = nwg >> 3;
  const int swz = (bid & 7) * cpx + (bid >> 3);
  const int rm = (swz / gridDim.x) * 64;
  const int cn = (swz % gridDim.x) * 128;
  const int wm = (w >> 1) * 32, wn = (w & 1) * 64;
  f32x4 acc[2][4] = {};

  for (int kk = 0; kk < K; kk += 128) {
#pragma unroll
    for (int r = 0; r < 4; ++r) {
      uint32_t o = (uint32_t)(r * 256 + tid) * 16;
      uint32_t row = o >> 8;
      uint32_t kb = ((o >> 4) & 15) ^ (row & 15);
      const bf16* src = A + (size_t)(rm + (int)row) * K + kk + kb * 8;
      GLOAD_LDS16(src, As + (o & 0xFFFFF800u) + ((o & 0x7F0u)));
    }
#pragma unroll
    for (int r = 0; r < 8; ++r) {
      uint32_t o = (uint32_t)(r * 256 + tid) * 16;
      uint32_t row = o >> 8;
      uint32_t kb = ((o >> 4) & 15) ^ (row & 15);
      int nrow = cn + (int)row;
      if (nrow >= N) nrow = N - 1;
      const bf16* src = Bt + (size_t)nrow * K + kk + kb * 8;
      GLOAD_LDS16(src, Bs + (o & 0xFFFFF800u) + ((o & 0x7F0u)));
    }
    __syncthreads();
#pragma unroll
    for (int s = 0; s < 4; ++s) {
      bf16x8 a[2], b[4];
#pragma unroll
      for (int m = 0; m < 2; ++m) {
        uint32_t row = wm + m * 16 + l15;
        uint32_t kb = (uint32_t)(s * 4 + l4);
        a[m] = *(const bf16x8*)(As + row * 256 + ((kb ^ (row & 15)) * 16));
      }
#pragma unroll
      for (int n = 0; n < 4; ++n) {
        uint32_t row = wn + n * 16 + l15;
        uint32_t kb = (uint32_t)(s * 4 + l4);
        b[n] = *(const bf16x8*)(Bs + row * 256 + ((kb ^ (row & 15)) * 16));
      }
      __builtin_amdgcn_s_setprio(1);
#pragma unroll
      for (int m = 0; m < 2; ++m)
#pragma unroll
        for (int n = 0; n < 4; ++n)
          acc[m][n] = __builtin_amdgcn_mfma_f32_16x16x32_bf16(a[m], b[n], acc[m][n], 0, 0, 0);
      __builtin_amdgcn_s_setprio(0);
    }
    __syncthreads();
  }

#pragma unroll
  for (int m = 0; m < 2; ++m)
#pragma unroll
    for (int n = 0; n < 4; ++n)
#pragma unroll
      for (int r = 0; r < 4; ++r) {
        int row = rm + wm + m * 16 + l4 * 4 + r;
        int col = cn + wn + n * 16 + l15;
        if (col < N) {
          float v = acc[m][n][r];
          size_t idx = (size_t)row * N + col;
          if constexpr (EPI == 2) {
            Cf[idx] += v;
          } else if constexpr (EPI == 4) {
            Cf[idx] += v + bias[col];
          } else if constexpr (EPI == 5) {
            Cb[idx] = (bf16)v;
          } else if constexpr (EPI == 6) {
            Cf2[idx] = Cf[idx] + v + bias[col];
          }
        }
      }
}

// ---------------- QKV postprocess (4 tokens/block): per (token, segment) RMSNorm (+scale+rope)
__global__ __launch_bounds__(256) void qkv_post(const bf16* __restrict__ qkv,
                                                const float* __restrict__ qg,
                                                const float* __restrict__ kg,
                                                const float* __restrict__ vg,
                                                bf16* __restrict__ Qo, bf16* __restrict__ Ko,
                                                bf16* __restrict__ Vo) {
  int lane = threadIdx.x & 63, wv = threadIdx.x >> 6;
  int t = blockIdx.x * 4 + wv, seg = blockIdx.y;
  int b = t >> 11, n = t & 2047;
  const bf16* base;
  const float* gamma;
  int len;
  if (seg < 8) { base = qkv + (size_t)t * 1344 + seg * 128; gamma = qg; len = 128; }
  else if (seg == 8) { base = qkv + (size_t)t * 1344 + 1024; gamma = kg; len = 128; }
  else { base = qkv + (size_t)t * 1344 + 1152; gamma = vg; len = 192; }
  float v0 = (float)base[lane], v1 = (float)base[lane + 64];
  float v2 = (len == 192) ? (float)base[lane + 128] : 0.f;
  float ss = wave_reduce_sum(v0 * v0 + v1 * v1 + v2 * v2);
  float rs = rsqrtf(ss / (float)len + EPSF);
  float n0 = v0 * rs * gamma[lane];
  float n1 = v1 * rs * gamma[lane + 64];
  if (seg < 8) {
    n0 *= 0.125f; n1 *= 0.125f;
    if (lane == 0) {
      float th = 0.1f * (float)n;
      float c = cosf(th), s_ = sinf(th);
      float r0 = n0 * c - n1 * s_, r1 = n1 * c + n0 * s_;
      n0 = r0; n1 = r1;
    }
    bf16* q = Qo + ((size_t)((b * 8 + seg) * 2048 + n)) * 128;
    q[lane] = (bf16)n0; q[lane + 64] = (bf16)n1;
  } else if (seg == 8) {
    if (lane == 0) {
      float th = 0.1f * (float)n;
      float c = cosf(th), s_ = sinf(th);
      float r0 = n0 * c - n1 * s_, r1 = n1 * c + n0 * s_;
      n0 = r0; n1 = r1;
    }
    bf16* k = Ko + ((size_t)(b * 2048 + n)) * 128;
    k[lane] = (bf16)n0; k[lane + 64] = (bf16)n1;
  } else {
    float n2 = v2 * rs * vg[lane + 128];
    bf16* vp = Vo + ((size_t)(b * 2048 + n)) * 192;
    vp[lane] = (bf16)n0; vp[lane + 64] = (bf16)n1; vp[lane + 128] = (bf16)n2;
  }
}

// ---------------- V transpose: V bf16 [2][2048][192] -> Vt [2][192][2048]
__global__ __launch_bounds__(256) void vtrans(const bf16* __restrict__ V, bf16* __restrict__ Vt) {
  __shared__ bf16 t[32][33];
  int b = blockIdx.z;
  int j0 = blockIdx.x * 32, d0 = blockIdx.y * 32;
  int tx = threadIdx.x, ty = threadIdx.y;
#pragma unroll
  for (int k = 0; k < 4; ++k)
    t[ty + k * 8][tx] = V[((size_t)b * 2048 + j0 + ty + k * 8) * 192 + d0 + tx];
  __syncthreads();
#pragma unroll
  for (int k = 0; k < 4; ++k)
    Vt[((size_t)b * 192 + d0 + ty + k * 8) * 2048 + j0 + tx] = t[tx][ty + k * 8];
}

// ---------------- pairwise bias, all 8 layers batched
__global__ void bias_pw8(const float* __restrict__ P, const float* __restrict__ G8,
                         const float* __restrict__ Wb8, float* __restrict__ Bout) {
  int j = blockIdx.x, i = blockIdx.y, b = blockIdx.z;
  int lane = threadIdx.x;
  const float* p = P + (((size_t)b * 128 + i) * 128 + j) * 128;
  float a0 = p[lane], a1 = p[lane + 64];
  float ss = wave_reduce_sum(a0 * a0 + a1 * a1);
  float rs = rsqrtf(ss * (1.f / 128.f) + EPSF);
  float pn0 = a0 * rs, pn1 = a1 * rs;
  __shared__ float gs[128];
  for (int d = 0; d < 8; ++d) {
    float x0 = pn0 * G8[d * 128 + lane], x1 = pn1 * G8[d * 128 + lane + 64];
    float g0 = 0.5f * x0 * (1.f + erff(x0 * 0.70710678118654752f));
    float g1 = 0.5f * x1 * (1.f + erff(x1 * 0.70710678118654752f));
    __syncthreads();
    gs[lane] = g0; gs[lane + 64] = g1;
    __syncthreads();
    int h = lane & 7;
    float acc = 0.f;
#pragma unroll
    for (int k = 0; k < 16; ++k) {
      int c = (lane >> 3) + k * 8;
      acc += gs[c] * Wb8[((size_t)d * 128 + c) * 8 + h];
    }
    acc += __shfl_xor(acc, 8, 64);
    acc += __shfl_xor(acc, 16, 64);
    acc += __shfl_xor(acc, 32, 64);
    if (lane < 8)
      Bout[((((size_t)d * 2 + b) * 8 + lane) * 128 + i) * 128 + j] = acc;
  }
}

// ---------------- attention (BI=64, full KV sweep, PV dv-split across waves)
__global__ __launch_bounds__(256, 3) void attn_k(const bf16* __restrict__ Q,
                                                 const bf16* __restrict__ Kg,
                                                 const bf16* __restrict__ Vt,
                                                 const float* __restrict__ Bias,
                                                 bf16* __restrict__ Out) {
  __shared__ __align__(16) char Ks[64 * 256];  // [64 j][128 k] swz16
  __shared__ __align__(16) char Vs[192 * 128]; // [192 dv][64 j] swz8
  __shared__ __align__(16) char Ps[64 * 128];  // [64 i][64 j] bf16, swz8 by (row&7)
  __shared__ float BiasS[4 * 128];             // pre-scaled by 0.57707801
  __shared__ float RowSum[64];
  int tid = threadIdx.x, lane = tid & 63, w = tid >> 6;
  int it = blockIdx.x, g = blockIdx.y, b = blockIdx.z;
  int i0 = it * 64;
  int l15 = lane & 15, l4 = lane >> 4;

  bf16x8 qf[4];
#pragma unroll
  for (int s = 0; s < 4; ++s)
    qf[s] = *(const bf16x8*)(Q + ((size_t)((b * 8 + g) * 2048 + i0 + w * 16 + l15)) * 128 + s * 32 + l4 * 8);

  if (tid < 128) {
    int r = tid >> 5, c = (tid & 31) * 4;
    float4 bv = *(const float4*)(Bias + ((size_t)((b * 8 + g) * 128) + (i0 >> 4) + r) * 128 + c);
    bv.x *= 0.57707801635558535f; bv.y *= 0.57707801635558535f;
    bv.z *= 0.57707801635558535f; bv.w *= 0.57707801635558535f;
    *(float4*)&BiasS[r * 128 + c] = bv;
  }

  f32x4 accO[4][3] = {};
  float lacc = 0.f;

  for (int jt = 0; jt < 32; ++jt) {
    int j0 = jt * 64;
#pragma unroll
    for (int r = 0; r < 4; ++r) {
      uint32_t o = (uint32_t)(r * 256 + tid) * 16;
      uint32_t row = o >> 8;
      uint32_t kb = ((o >> 4) & 15) ^ (row & 15);
      const bf16* src = Kg + ((size_t)b * 2048 + j0 + (int)row) * 128 + kb * 8;
      GLOAD_LDS16(src, Ks + (o & 0xFFFFFC00u));
    }
#pragma unroll
    for (int r = 0; r < 6; ++r) {
      uint32_t o = (uint32_t)(r * 256 + tid) * 16;
      uint32_t dv = o >> 7;
      uint32_t kb = ((o >> 4) & 7) ^ (dv & 7);
      const bf16* src = Vt + ((size_t)b * 192 + dv) * 2048 + j0 + kb * 8;
      GLOAD_LDS16(src, Vs + (o & 0xFFFFFC00u));
    }
    __syncthreads();

    // QK^T swapped: accS[n] = mfma(kf[n], qf[s])  (row=j, col=i=l15)
    f32x4 accS[4] = {};
#pragma unroll
    for (int s = 0; s < 4; ++s) {
      bf16x8 kf[4];
#pragma unroll
      for (int n = 0; n < 4; ++n) {
        uint32_t row = n * 16 + l15;
        uint32_t kb = (uint32_t)(s * 4 + l4);
        kf[n] = *(const bf16x8*)(Ks + row * 256 + (kb ^ (row & 15)) * 16);
      }
      __builtin_amdgcn_s_setprio(1);
#pragma unroll
      for (int n = 0; n < 4; ++n)
        accS[n] = __builtin_amdgcn_mfma_f32_16x16x32_bf16(kf[n], qf[s], accS[n], 0, 0, 0);
      __builtin_amdgcn_s_setprio(0);
    }

    // softclamp + exp -> packed b64 P-writes (wave's own rows) + per-lane sums
#pragma unroll
    for (int n = 0; n < 4; ++n) {
      float biaS = BiasS[w * 128 + jt * 4 + n];
      bf16x4 pk;
#pragma unroll
      for (int r = 0; r < 4; ++r) {
        float t1 = __builtin_fmaf(0.57707801635558535f, accS[n][r], biaS);
        float e1 = exp2f(t1);
        float rr = __builtin_amdgcn_rcpf(e1 + 1.0f);
        float pv = exp2f(-14.426950408889634f * rr);
        lacc += pv;
        pk[r] = (bf16)pv;
      }
      uint32_t prow = (uint32_t)(w * 16 + l15);
      uint32_t byteo = prow * 128 + (uint32_t)(n * 16 + l4 * 4) * 2;
      byteo ^= (prow & 7) << 4;
      *(bf16x4*)(Ps + byteo) = pk;
    }
    __syncthreads();  // P now complete for all 64 rows

    // PV dv-split: wave w computes accO over all 64 q-rows x its 48 dv
#pragma unroll
    for (int s = 0; s < 2; ++s) {
      bf16x8 pa[4];
#pragma unroll
      for (int m = 0; m < 4; ++m) {
        uint32_t prow = (uint32_t)(m * 16 + l15);
        uint32_t byteo = prow * 128 + (uint32_t)(s * 64 + l4 * 16);
        byteo ^= (prow & 7) << 4;
        pa[m] = *(const bf16x8*)(Ps + byteo);
      }
#pragma unroll
      for (int n = 0; n < 3; ++n) {
        uint32_t dvr = (uint32_t)(w * 48 + n * 16 + l15);
        uint32_t kb = (uint32_t)(s * 4 + l4);
        bf16x8 vf = *(const bf16x8*)(Vs + dvr * 128 + (kb ^ (dvr & 7)) * 16);
        __builtin_amdgcn_s_setprio(1);
#pragma unroll
        for (int m = 0; m < 4; ++m)
          accO[m][n] = __builtin_amdgcn_mfma_f32_16x16x32_bf16(vf, pa[m], accO[m][n], 0, 0, 0);
        __builtin_amdgcn_s_setprio(0);
      }
    }
    __syncthreads();
  }

  lacc += __shfl_xor(lacc, 16, 64);
  lacc += __shfl_xor(lacc, 32, 64);
  if (l4 == 0) RowSum[w * 16 + l15] = lacc;
  __syncthreads();

#pragma unroll
  for (int m = 0; m < 4; ++m) {
    int i = i0 + m * 16 + l15;
    float rl = __builtin_amdgcn_rcpf(RowSum[m * 16 + l15]);
#pragma unroll
    for (int n = 0; n < 3; ++n) {
      bf16x4 ok;
#pragma unroll
      for (int r = 0; r < 4; ++r) ok[r] = (bf16)(accO[m][n][r] * rl);
      int dv = w * 48 + n * 16 + l4 * 4;
      *(bf16x4*)(Out + ((size_t)(b * 2048 + i)) * 1536 + g * 192 + dv) = ok;
    }
  }
}

// =============================================================================
extern "C" void kernel_launch(void* const* d_in, const int* in_sizes, int n_in,
                              void* d_out, int out_size, void* d_ws, size_t ws_size,
                              hipStream_t stream) {
  (void)in_sizes; (void)n_in; (void)out_size;
  const float* x_in = (const float*)d_in[0];
  const float* pairwise = (const float*)d_in[1];
  const float* w_qkv = (const float*)d_in[2];
  const float* q_gamma = (const float*)d_in[3];
  const float* k_gamma = (const float*)d_in[4];
  const float* v_gamma = (const float*)d_in[5];
  const float* bias_gamma = (const float*)d_in[6];
  const float* w_bias = (const float*)d_in[7];
  const float* w_out = (const float*)d_in[8];
  const float* attn_pre = (const float*)d_in[9];
  const float* ff_pre = (const float*)d_in[10];
  const float* w_ff1 = (const float*)d_in[11];
  const float* b_ff1 = (const float*)d_in[12];
  const float* w_ff2 = (const float*)d_in[13];
  const float* b_ff2 = (const float*)d_in[14];

  char* p = (char*)d_ws;
  auto alloc = [&](size_t bytes) {
    char* r = p;
    p += (bytes + 255) & ~(size_t)255;
    return r;
  };
  bf16* wT_qkv = (bf16*)alloc(8ull * 1344 * 1536 * 2);
  bf16* wT_out = (bf16*)alloc(8ull * 1536 * 1536 * 2);
  bf16* wT_ff1 = (bf16*)alloc(8ull * 3072 * 1536 * 2);
  bf16* wT_ff2 = (bf16*)alloc(8ull * 1536 * 3072 * 2);
  float* x_ws = (float*)alloc(4096ull * 1536 * 4);
  bf16* xn = (bf16*)alloc(4096ull * 1536 * 2);
  bf16* qkvb = (bf16*)alloc(4096ull * 1344 * 2);
  bf16* qb = (bf16*)alloc(2ull * 8 * 2048 * 128 * 2);
  bf16* kb = (bf16*)alloc(2ull * 2048 * 128 * 2);
  bf16* vb = (bf16*)alloc(2ull * 2048 * 192 * 2);
  bf16* vtb = (bf16*)alloc(2ull * 192 * 2048 * 2);
  float* biasb8 = (float*)alloc(8ull * 2 * 8 * 128 * 128 * 4);
  bf16* attn_o = (bf16*)alloc(4096ull * 1536 * 2);
  bf16* hb = (bf16*)alloc(4096ull * 3072 * 2);
  if ((size_t)(p - (char*)d_ws) > ws_size) return;  // workspace too small

  // weight casts (transposed to [N][K] bf16)
  wcast_t<<<dim3(42, 48, 8), dim3(32, 8), 0, stream>>>(w_qkv, wT_qkv, 1536, 1344);
  wcast_t<<<dim3(48, 48, 8), dim3(32, 8), 0, stream>>>(w_out, wT_out, 1536, 1536);
  wcast_t<<<dim3(96, 48, 8), dim3(32, 8), 0, stream>>>(w_ff1, wT_ff1, 1536, 3072);
  wcast_t<<<dim3(48, 96, 8), dim3(32, 8), 0, stream>>>(w_ff2, wT_ff2, 3072, 1536);

  // all-layer pairwise bias
  bias_pw8<<<dim3(128, 128, 2), 64, 0, stream>>>(pairwise, bias_gamma, w_bias, biasb8);

  hipMemcpyAsync(x_ws, x_in, 4096ull * 1536 * 4, hipMemcpyDeviceToDevice, stream);

  for (int d = 0; d < 8; ++d) {
    const bf16* wq = wT_qkv + (size_t)d * 1344 * 1536;
    const bf16* wo = wT_out + (size_t)d * 1536 * 1536;
    const bf16* w1 = wT_ff1 + (size_t)d * 3072 * 1536;
    const bf16* w2 = wT_ff2 + (size_t)d * 1536 * 3072;

    rmsnorm_k<<<1024, 256, 0, stream>>>(x_ws, attn_pre + d * 1536, xn);
    gemm_bt64<5><<<dim3(11, 64), 256, 0, stream>>>(xn, wq, nullptr, qkvb, nullptr, nullptr, 4096, 1344, 1536);
    qkv_post<<<dim3(1024, 10), 256, 0, stream>>>(qkvb, q_gamma + d * 128, k_gamma + d * 128,
                                                 v_gamma + d * 192, qb, kb, vb);
    vtrans<<<dim3(64, 6, 2), dim3(32, 8), 0, stream>>>(vb, vtb);
    attn_k<<<dim3(32, 8, 2), 256, 0, stream>>>(qb, kb, vtb,
                                               biasb8 + (size_t)d * 2 * 8 * 128 * 128, attn_o);
    gemm_bt64<2><<<dim3(12, 64), 256, 0, stream>>>(attn_o, wo, x_ws, nullptr, nullptr, nullptr, 4096, 1536, 1536);
    rmsnorm_k<<<1024, 256, 0, stream>>>(x_ws, ff_pre + d * 1536, xn);
    gemm_bt<3><<<dim3(24, 32), 256, 0, stream>>>(xn, w1, nullptr, hb, b_ff1 + d * 3072, 4096, 3072, 1536);
    if (d < 7) {
      gemm_bt64<4><<<dim3(12, 64), 256, 0, stream>>>(hb, w2, x_ws, nullptr, b_ff2 + d * 1536, nullptr, 4096, 1536, 3072);
    } else {
      // last layer: write final residual sum directly into d_out (skip the copy)
      gemm_bt64<6><<<dim3(12, 64), 256, 0, stream>>>(hb, w2, x_ws, nullptr, b_ff2 + d * 1536,
                                                     (float*)d_out, 4096, 1536, 3072);
    }
  }
}